// Round 3
// baseline (2663.458 us; speedup 1.0000x reference)
//
#include <hip/hip_runtime.h>

// Problem constants (from reference setup_inputs)
constexpr int kB   = 32;
constexpr int kT   = 1002;
constexpr int kD   = 16;
constexpr int kE   = 32;
constexpr int kH   = 64;
constexpr int kLen = kT - 2;        // 1000
constexpr int kN   = kB * kLen;     // 32000
constexpr float kSlope = 0.2f;
constexpr int kTPB = 128;           // 2 waves / block

// Each block: 64 tasks (same d), 2 waves. Wave `half` computes hidden rows
// [32*half, 32*half+32) for all 64 tasks -> weight reads stay wave-uniform
// (scalar s_load). Boundary activations live once per TASK in LDS
// (buf[t][65], 16.6 KB/block -> ~9 blocks/CU vs round-2's 4-5), doubling
// wave-level latency hiding. Heads are fused into L2/jacL2 as per-wave
// partials combined via a tiny LDS exchange. Gates are per-thread 32-bit
// sign masks so the single LDS buffer can be reused by the Jacobian chain.
__global__ __launch_bounds__(kTPB, 4) void np_prior_kernel(
    const float* __restrict__ x, const float* __restrict__ emb,
    const float* __restrict__ W0, const float* __restrict__ b0,
    const float* __restrict__ W1, const float* __restrict__ b1,
    const float* __restrict__ W2, const float* __restrict__ b2,
    const float* __restrict__ Wo, const float* __restrict__ bo,
    float* __restrict__ out_res, float* __restrict__ out_ld)
{
    __shared__ float buf[64][kH + 1];  // [task][h], pad -> (t+j)%32 banks: 2 lanes/bank, free
    __shared__ float s1res[64];        // half-1 head partials
    __shared__ float s1dj[64];

    const int tid  = threadIdx.x;
    const int t    = tid & 63;         // task slot within block
    const int half = tid >> 6;         // which 32 hidden rows this wave owns
    const int i0   = half * 32;
    const int n    = blockIdx.x * 64 + t;   // 500*64 == 32000 exactly
    const int d    = blockIdx.y;

    const int bb  = n / kLen;
    const int tt  = n - bb * kLen;
    const int src = bb * kT + tt + 2;       // LAGS offset

    const float xv = x[(size_t)src * kD + d];

    const float* __restrict__ w0  = W0 + d * kH * (kE + 1);
    const float* __restrict__ w1  = W1 + d * kH * kH;
    const float* __restrict__ w2  = W2 + d * kH * kH;
    const float* __restrict__ wo  = Wo + d * kH;
    const float* __restrict__ pb0 = b0 + d * kH;
    const float* __restrict__ pb1 = b1 + d * kH;
    const float* __restrict__ pb2 = b2 + d * kH;

    // embedding row: 8x float4 (row is 128 B, aligned); dies after L0
    float er[kE];
    {
        const float4* __restrict__ ep4 =
            reinterpret_cast<const float4*>(emb + (size_t)src * kE);
        #pragma unroll
        for (int e4 = 0; e4 < kE / 4; ++e4) {
            float4 v = ep4[e4];
            er[4 * e4 + 0] = v.x; er[4 * e4 + 1] = v.y;
            er[4 * e4 + 2] = v.z; er[4 * e4 + 3] = v.w;
        }
    }

    unsigned int m0 = 0u, m1 = 0u, m2 = 0u;

    // ---- L0: rows i0..i0+31 of z0 = W0 @ [emb, x] + b0 ----
    #pragma unroll 4
    for (int ii = 0; ii < 32; ++ii) {
        const int i = i0 + ii;
        const float* wr = w0 + i * (kE + 1);
        float acc = pb0[i];
        #pragma unroll
        for (int e = 0; e < kE; ++e) acc = fmaf(wr[e], er[e], acc);
        acc = fmaf(wr[kE], xv, acc);
        const bool g = (acc >= 0.f);
        m0 |= (unsigned int)g << ii;
        buf[t][i] = g ? acc : acc * kSlope;
    }
    __syncthreads();

    float a[kH];
    #pragma unroll
    for (int j = 0; j < kH; ++j) a[j] = buf[t][j];
    __syncthreads();

    // ---- L1 ----
    #pragma unroll 4
    for (int ii = 0; ii < 32; ++ii) {
        const int i = i0 + ii;
        const float* wr = w1 + i * kH;
        float acc = pb1[i];
        #pragma unroll
        for (int j = 0; j < kH; ++j) acc = fmaf(wr[j], a[j], acc);
        const bool g = (acc >= 0.f);
        m1 |= (unsigned int)g << ii;
        buf[t][i] = g ? acc : acc * kSlope;
    }
    __syncthreads();

    #pragma unroll
    for (int j = 0; j < kH; ++j) a[j] = buf[j == j ? t : t][j];  // buf[t][j]
    __syncthreads();

    // ---- L2 + fused forward head (a2 never stored) ----
    float resp = (half == 0) ? bo[d] : 0.f;
    #pragma unroll 4
    for (int ii = 0; ii < 32; ++ii) {
        const int i = i0 + ii;
        const float* wr = w2 + i * kH;
        float acc = pb2[i];
        #pragma unroll
        for (int j = 0; j < kH; ++j) acc = fmaf(wr[j], a[j], acc);
        const bool g = (acc >= 0.f);
        m2 |= (unsigned int)g << ii;
        resp = fmaf(wo[i], g ? acc : acc * kSlope, resp);
    }

    // ---- Jacobian t0 = g0 * W0[:, -1] (safe: all L1-buf reads completed
    //      at the barrier after the a-load above; L2 touched no LDS) ----
    #pragma unroll 4
    for (int ii = 0; ii < 32; ++ii) {
        const int i = i0 + ii;
        buf[t][i] = (((m0 >> ii) & 1u) ? 1.f : kSlope) * w0[i * (kE + 1) + kE];
    }
    __syncthreads();

    #pragma unroll
    for (int j = 0; j < kH; ++j) a[j] = buf[t][j];
    __syncthreads();

    // ---- jac L1: t1 = g1 * (W1 @ t0) ----
    #pragma unroll 4
    for (int ii = 0; ii < 32; ++ii) {
        const int i = i0 + ii;
        const float* wr = w1 + i * kH;
        float acc = 0.f;
        #pragma unroll
        for (int j = 0; j < kH; ++j) acc = fmaf(wr[j], a[j], acc);
        buf[t][i] = (((m1 >> ii) & 1u) ? 1.f : kSlope) * acc;
    }
    __syncthreads();

    #pragma unroll
    for (int j = 0; j < kH; ++j) a[j] = buf[t][j];
    __syncthreads();

    // ---- jac L2 + fused Jacobian head ----
    float djp = 0.f;
    #pragma unroll 4
    for (int ii = 0; ii < 32; ++ii) {
        const int i = i0 + ii;
        const float* wr = w2 + i * kH;
        float acc = 0.f;
        #pragma unroll
        for (int j = 0; j < kH; ++j) acc = fmaf(wr[j], a[j], acc);
        djp = fmaf(wo[i], (((m2 >> ii) & 1u) ? 1.f : kSlope) * acc, djp);
    }

    // combine the two waves' head partials
    if (half == 1) { s1res[t] = resp; s1dj[t] = djp; }
    __syncthreads();
    if (half == 0) {
        out_res[(size_t)n * kD + d] = resp + s1res[t];
        const float dj = djp + s1dj[t];
        atomicAdd(&out_ld[n], __logf(fabsf(dj)));
    }
}

extern "C" void kernel_launch(void* const* d_in, const int* in_sizes, int n_in,
                              void* d_out, int out_size, void* d_ws, size_t ws_size,
                              hipStream_t stream) {
    const float* x  = (const float*)d_in[0];
    const float* em = (const float*)d_in[1];
    const float* W0 = (const float*)d_in[2];
    const float* b0 = (const float*)d_in[3];
    const float* W1 = (const float*)d_in[4];
    const float* b1 = (const float*)d_in[5];
    const float* W2 = (const float*)d_in[6];
    const float* b2 = (const float*)d_in[7];
    const float* Wo = (const float*)d_in[8];
    const float* bo = (const float*)d_in[9];

    float* out_res = (float*)d_out;                    // [N, D] residuals
    float* out_ld  = (float*)d_out + (size_t)kN * kD;  // [N] log|det J|

    // logdet accumulated with atomics across the 16 d-blocks -> zero it first
    hipMemsetAsync(out_ld, 0, kN * sizeof(float), stream);

    dim3 grid(kN / 64, kD);
    np_prior_kernel<<<grid, dim3(kTPB), 0, stream>>>(
        x, em, W0, b0, W1, b1, W2, b2, Wo, bo, out_res, out_ld);
}

// Round 4
// 1190.511 us; speedup vs baseline: 2.2372x; 2.2372x over previous
//
#include <hip/hip_runtime.h>

// Problem constants (from reference setup_inputs)
constexpr int kB   = 32;
constexpr int kT   = 1002;
constexpr int kD   = 16;
constexpr int kE   = 32;
constexpr int kH   = 64;
constexpr int kLen = kT - 2;        // 1000
constexpr int kN   = kB * kLen;     // 32000
constexpr float kSlope = 0.2f;
constexpr int kTPB = 128;           // 2 waves / block

// Each block: 64 tasks (same d), 2 waves. Wave `half` computes hidden rows
// [32*half, 32*half+32) for all 64 tasks -> weight reads stay wave-uniform
// (scalar s_load). Boundary activations live once per TASK in LDS
// (buf[t][65], 17 KB/block). Heads fused into L2/jacL2 as per-wave partials
// combined via a tiny LDS exchange; gates as per-thread 32-bit sign masks.
//
// __launch_bounds__(128, 2): cap 256 VGPRs. Round 3 used (128,4) -> allocator
// snapped to the 64-VGPR bucket and spilled a[64] to scratch (7.5 GB of HBM
// traffic, 3.6x regression). Live set is ~90-110 VGPRs; do NOT cap below 128.
__global__ __launch_bounds__(kTPB, 2) void np_prior_kernel(
    const float* __restrict__ x, const float* __restrict__ emb,
    const float* __restrict__ W0, const float* __restrict__ b0,
    const float* __restrict__ W1, const float* __restrict__ b1,
    const float* __restrict__ W2, const float* __restrict__ b2,
    const float* __restrict__ Wo, const float* __restrict__ bo,
    float* __restrict__ out_res, float* __restrict__ out_ld)
{
    __shared__ float buf[64][kH + 1];  // [task][h]; pad -> 2 lanes/bank (free, m136)
    __shared__ float s1res[64];        // half-1 head partials
    __shared__ float s1dj[64];

    const int tid  = threadIdx.x;
    const int t    = tid & 63;         // task slot within block
    const int half = tid >> 6;         // which 32 hidden rows this wave owns
    const int i0   = half * 32;
    const int n    = blockIdx.x * 64 + t;   // 500*64 == 32000 exactly
    const int d    = blockIdx.y;

    const int bb  = n / kLen;
    const int tt  = n - bb * kLen;
    const int src = bb * kT + tt + 2;       // LAGS offset

    const float xv = x[(size_t)src * kD + d];

    const float* __restrict__ w0  = W0 + d * kH * (kE + 1);
    const float* __restrict__ w1  = W1 + d * kH * kH;
    const float* __restrict__ w2  = W2 + d * kH * kH;
    const float* __restrict__ wo  = Wo + d * kH;
    const float* __restrict__ pb0 = b0 + d * kH;
    const float* __restrict__ pb1 = b1 + d * kH;
    const float* __restrict__ pb2 = b2 + d * kH;

    // embedding row: 8x float4 (row is 128 B, aligned); dies after L0
    float er[kE];
    {
        const float4* __restrict__ ep4 =
            reinterpret_cast<const float4*>(emb + (size_t)src * kE);
        #pragma unroll
        for (int e4 = 0; e4 < kE / 4; ++e4) {
            float4 v = ep4[e4];
            er[4 * e4 + 0] = v.x; er[4 * e4 + 1] = v.y;
            er[4 * e4 + 2] = v.z; er[4 * e4 + 3] = v.w;
        }
    }

    unsigned int m0 = 0u, m1 = 0u, m2 = 0u;

    // ---- L0: rows i0..i0+31 of z0 = W0 @ [emb, x] + b0 ----
    #pragma unroll 4
    for (int ii = 0; ii < 32; ++ii) {
        const int i = i0 + ii;
        const float* wr = w0 + i * (kE + 1);
        float acc = pb0[i];
        #pragma unroll
        for (int e = 0; e < kE; ++e) acc = fmaf(wr[e], er[e], acc);
        acc = fmaf(wr[kE], xv, acc);
        const bool g = (acc >= 0.f);
        m0 |= (unsigned int)g << ii;
        buf[t][i] = g ? acc : acc * kSlope;
    }
    __syncthreads();

    float a[kH];
    #pragma unroll
    for (int j = 0; j < kH; ++j) a[j] = buf[t][j];
    __syncthreads();

    // ---- L1 ----
    #pragma unroll 4
    for (int ii = 0; ii < 32; ++ii) {
        const int i = i0 + ii;
        const float* wr = w1 + i * kH;
        float acc = pb1[i];
        #pragma unroll
        for (int j = 0; j < kH; ++j) acc = fmaf(wr[j], a[j], acc);
        const bool g = (acc >= 0.f);
        m1 |= (unsigned int)g << ii;
        buf[t][i] = g ? acc : acc * kSlope;
    }
    __syncthreads();

    #pragma unroll
    for (int j = 0; j < kH; ++j) a[j] = buf[t][j];
    __syncthreads();

    // ---- L2 + fused forward head (a2 never stored) ----
    float resp = (half == 0) ? bo[d] : 0.f;
    #pragma unroll 4
    for (int ii = 0; ii < 32; ++ii) {
        const int i = i0 + ii;
        const float* wr = w2 + i * kH;
        float acc = pb2[i];
        #pragma unroll
        for (int j = 0; j < kH; ++j) acc = fmaf(wr[j], a[j], acc);
        const bool g = (acc >= 0.f);
        m2 |= (unsigned int)g << ii;
        resp = fmaf(wo[i], g ? acc : acc * kSlope, resp);
    }

    // ---- Jacobian t0 = g0 * W0[:, -1] ----
    #pragma unroll 4
    for (int ii = 0; ii < 32; ++ii) {
        const int i = i0 + ii;
        buf[t][i] = (((m0 >> ii) & 1u) ? 1.f : kSlope) * w0[i * (kE + 1) + kE];
    }
    __syncthreads();

    #pragma unroll
    for (int j = 0; j < kH; ++j) a[j] = buf[t][j];
    __syncthreads();

    // ---- jac L1: t1 = g1 * (W1 @ t0) ----
    #pragma unroll 4
    for (int ii = 0; ii < 32; ++ii) {
        const int i = i0 + ii;
        const float* wr = w1 + i * kH;
        float acc = 0.f;
        #pragma unroll
        for (int j = 0; j < kH; ++j) acc = fmaf(wr[j], a[j], acc);
        buf[t][i] = (((m1 >> ii) & 1u) ? 1.f : kSlope) * acc;
    }
    __syncthreads();

    #pragma unroll
    for (int j = 0; j < kH; ++j) a[j] = buf[t][j];
    __syncthreads();

    // ---- jac L2 + fused Jacobian head ----
    float djp = 0.f;
    #pragma unroll 4
    for (int ii = 0; ii < 32; ++ii) {
        const int i = i0 + ii;
        const float* wr = w2 + i * kH;
        float acc = 0.f;
        #pragma unroll
        for (int j = 0; j < kH; ++j) acc = fmaf(wr[j], a[j], acc);
        djp = fmaf(wo[i], (((m2 >> ii) & 1u) ? 1.f : kSlope) * acc, djp);
    }

    // combine the two waves' head partials
    if (half == 1) { s1res[t] = resp; s1dj[t] = djp; }
    __syncthreads();
    if (half == 0) {
        out_res[(size_t)n * kD + d] = resp + s1res[t];
        const float dj = djp + s1dj[t];
        atomicAdd(&out_ld[n], __logf(fabsf(dj)));
    }
}

extern "C" void kernel_launch(void* const* d_in, const int* in_sizes, int n_in,
                              void* d_out, int out_size, void* d_ws, size_t ws_size,
                              hipStream_t stream) {
    const float* x  = (const float*)d_in[0];
    const float* em = (const float*)d_in[1];
    const float* W0 = (const float*)d_in[2];
    const float* b0 = (const float*)d_in[3];
    const float* W1 = (const float*)d_in[4];
    const float* b1 = (const float*)d_in[5];
    const float* W2 = (const float*)d_in[6];
    const float* b2 = (const float*)d_in[7];
    const float* Wo = (const float*)d_in[8];
    const float* bo = (const float*)d_in[9];

    float* out_res = (float*)d_out;                    // [N, D] residuals
    float* out_ld  = (float*)d_out + (size_t)kN * kD;  // [N] log|det J|

    // logdet accumulated with atomics across the 16 d-blocks -> zero it first
    hipMemsetAsync(out_ld, 0, kN * sizeof(float), stream);

    dim3 grid(kN / 64, kD);
    np_prior_kernel<<<grid, dim3(kTPB), 0, stream>>>(
        x, em, W0, b0, W1, b1, W2, b2, Wo, bo, out_res, out_ld);
}

// Round 5
// 738.414 us; speedup vs baseline: 3.6070x; 1.6123x over previous
//
#include <hip/hip_runtime.h>

// Problem constants (from reference setup_inputs)
constexpr int kB   = 32;
constexpr int kT   = 1002;
constexpr int kD   = 16;
constexpr int kE   = 32;
constexpr int kH   = 64;
constexpr int kLen = kT - 2;        // 1000
constexpr int kN   = kB * kLen;     // 32000
constexpr float kSlope = 0.2f;
constexpr int kTPB = 128;           // 2 waves / block

// Each block: 64 tasks (same d), 2 waves. Wave `half` computes hidden rows
// [32*half, 32*half+32) for all 64 tasks. Boundary activations live once per
// TASK in LDS (buf[t][65], 17 KB/block -> 9 blocks/CU). Heads fused into
// L2/jacL2 as per-wave partials combined via a tiny LDS exchange; gates as
// per-thread 32-bit sign masks.
//
// CRITICAL (round-4 post-mortem): `half` MUST be scalarized via
// readfirstlane. Without it the compiler treats i0 = half*32 as per-lane,
// every weight address becomes a VGPR address, weight rows load through
// VGPRs instead of SGPR s_load -> ~75 floats/task of scratch spill
// (178 MB HBM write traffic, 1.6x slower than the 2-wave-per-task variant).
//
// __launch_bounds__(128, 2): allocator targets the LDS-derived occupancy
// (9 blocks/CU -> 128 VGPR budget); live set ~85 fits. Do NOT set min
// waves >= 4 (round 3: snapped to 64 VGPR, spilled everything, 3.6x).
__global__ __launch_bounds__(kTPB, 2) void np_prior_kernel(
    const float* __restrict__ x, const float* __restrict__ emb,
    const float* __restrict__ W0, const float* __restrict__ b0,
    const float* __restrict__ W1, const float* __restrict__ b1,
    const float* __restrict__ W2, const float* __restrict__ b2,
    const float* __restrict__ Wo, const float* __restrict__ bo,
    float* __restrict__ out_res, float* __restrict__ out_ld)
{
    __shared__ float buf[64][kH + 1];  // [task][h]; pad -> 2 lanes/bank (free)
    __shared__ float s1res[64];        // half-1 head partials
    __shared__ float s1dj[64];

    const int tid  = threadIdx.x;
    const int t    = tid & 63;         // task slot within block (per-lane)
    // wave-uniform by construction; force the compiler to see it as scalar
    const int half = __builtin_amdgcn_readfirstlane(tid >> 6);
    const int i0   = half * 32;        // SGPR -> weight addrs stay scalar
    const int n    = blockIdx.x * 64 + t;   // 500*64 == 32000 exactly
    const int d    = blockIdx.y;

    const int bb  = n / kLen;
    const int tt  = n - bb * kLen;
    const int src = bb * kT + tt + 2;       // LAGS offset

    const float xv = x[(size_t)src * kD + d];

    const float* __restrict__ w0  = W0 + d * kH * (kE + 1);
    const float* __restrict__ w1  = W1 + d * kH * kH;
    const float* __restrict__ w2  = W2 + d * kH * kH;
    const float* __restrict__ wo  = Wo + d * kH;
    const float* __restrict__ pb0 = b0 + d * kH;
    const float* __restrict__ pb1 = b1 + d * kH;
    const float* __restrict__ pb2 = b2 + d * kH;

    // embedding row: 8x float4 (row is 128 B, aligned); dies after L0
    float er[kE];
    {
        const float4* __restrict__ ep4 =
            reinterpret_cast<const float4*>(emb + (size_t)src * kE);
        #pragma unroll
        for (int e4 = 0; e4 < kE / 4; ++e4) {
            float4 v = ep4[e4];
            er[4 * e4 + 0] = v.x; er[4 * e4 + 1] = v.y;
            er[4 * e4 + 2] = v.z; er[4 * e4 + 3] = v.w;
        }
    }

    unsigned int m0 = 0u, m1 = 0u, m2 = 0u;

    // ---- L0: rows i0..i0+31 of z0 = W0 @ [emb, x] + b0 ----
    #pragma unroll 4
    for (int ii = 0; ii < 32; ++ii) {
        const int i = i0 + ii;
        const float* wr = w0 + i * (kE + 1);
        float acc = pb0[i];
        #pragma unroll
        for (int e = 0; e < kE; ++e) acc = fmaf(wr[e], er[e], acc);
        acc = fmaf(wr[kE], xv, acc);
        const bool g = (acc >= 0.f);
        m0 |= (unsigned int)g << ii;
        buf[t][i] = g ? acc : acc * kSlope;
    }
    __syncthreads();

    float a[kH];
    #pragma unroll
    for (int j = 0; j < kH; ++j) a[j] = buf[t][j];
    __syncthreads();

    // ---- L1 ----
    #pragma unroll 4
    for (int ii = 0; ii < 32; ++ii) {
        const int i = i0 + ii;
        const float* wr = w1 + i * kH;
        float acc = pb1[i];
        #pragma unroll
        for (int j = 0; j < kH; ++j) acc = fmaf(wr[j], a[j], acc);
        const bool g = (acc >= 0.f);
        m1 |= (unsigned int)g << ii;
        buf[t][i] = g ? acc : acc * kSlope;
    }
    __syncthreads();

    #pragma unroll
    for (int j = 0; j < kH; ++j) a[j] = buf[t][j];
    __syncthreads();

    // ---- L2 + fused forward head (a2 never stored) ----
    float resp = (half == 0) ? bo[d] : 0.f;
    #pragma unroll 4
    for (int ii = 0; ii < 32; ++ii) {
        const int i = i0 + ii;
        const float* wr = w2 + i * kH;
        float acc = pb2[i];
        #pragma unroll
        for (int j = 0; j < kH; ++j) acc = fmaf(wr[j], a[j], acc);
        const bool g = (acc >= 0.f);
        m2 |= (unsigned int)g << ii;
        resp = fmaf(wo[i], g ? acc : acc * kSlope, resp);
    }

    // ---- Jacobian t0 = g0 * W0[:, -1] (all buf reads done at the barrier
    //      after the a-load above; L2 touched no LDS) ----
    #pragma unroll 4
    for (int ii = 0; ii < 32; ++ii) {
        const int i = i0 + ii;
        buf[t][i] = (((m0 >> ii) & 1u) ? 1.f : kSlope) * w0[i * (kE + 1) + kE];
    }
    __syncthreads();

    #pragma unroll
    for (int j = 0; j < kH; ++j) a[j] = buf[t][j];
    __syncthreads();

    // ---- jac L1: t1 = g1 * (W1 @ t0) ----
    #pragma unroll 4
    for (int ii = 0; ii < 32; ++ii) {
        const int i = i0 + ii;
        const float* wr = w1 + i * kH;
        float acc = 0.f;
        #pragma unroll
        for (int j = 0; j < kH; ++j) acc = fmaf(wr[j], a[j], acc);
        buf[t][i] = (((m1 >> ii) & 1u) ? 1.f : kSlope) * acc;
    }
    __syncthreads();

    #pragma unroll
    for (int j = 0; j < kH; ++j) a[j] = buf[t][j];
    __syncthreads();

    // ---- jac L2 + fused Jacobian head ----
    float djp = 0.f;
    #pragma unroll 4
    for (int ii = 0; ii < 32; ++ii) {
        const int i = i0 + ii;
        const float* wr = w2 + i * kH;
        float acc = 0.f;
        #pragma unroll
        for (int j = 0; j < kH; ++j) acc = fmaf(wr[j], a[j], acc);
        djp = fmaf(wo[i], (((m2 >> ii) & 1u) ? 1.f : kSlope) * acc, djp);
    }

    // combine the two waves' head partials
    if (half == 1) { s1res[t] = resp; s1dj[t] = djp; }
    __syncthreads();
    if (half == 0) {
        out_res[(size_t)n * kD + d] = resp + s1res[t];
        const float dj = djp + s1dj[t];
        atomicAdd(&out_ld[n], __logf(fabsf(dj)));
    }
}

extern "C" void kernel_launch(void* const* d_in, const int* in_sizes, int n_in,
                              void* d_out, int out_size, void* d_ws, size_t ws_size,
                              hipStream_t stream) {
    const float* x  = (const float*)d_in[0];
    const float* em = (const float*)d_in[1];
    const float* W0 = (const float*)d_in[2];
    const float* b0 = (const float*)d_in[3];
    const float* W1 = (const float*)d_in[4];
    const float* b1 = (const float*)d_in[5];
    const float* W2 = (const float*)d_in[6];
    const float* b2 = (const float*)d_in[7];
    const float* Wo = (const float*)d_in[8];
    const float* bo = (const float*)d_in[9];

    float* out_res = (float*)d_out;                    // [N, D] residuals
    float* out_ld  = (float*)d_out + (size_t)kN * kD;  // [N] log|det J|

    // logdet accumulated with atomics across the 16 d-blocks -> zero it first
    hipMemsetAsync(out_ld, 0, kN * sizeof(float), stream);

    dim3 grid(kN / 64, kD);
    np_prior_kernel<<<grid, dim3(kTPB), 0, stream>>>(
        x, em, W0, b0, W1, b1, W2, b2, Wo, bo, out_res, out_ld);
}

// Round 7
// 248.479 us; speedup vs baseline: 10.7190x; 2.9717x over previous
//
#include <hip/hip_runtime.h>

// ---- problem constants ----
constexpr int   kT    = 1002;
constexpr int   kD    = 16;
constexpr int   kE    = 32;
constexpr int   kH    = 64;
constexpr int   kLen  = kT - 2;     // 1000
constexpr int   kN    = 32 * kLen;  // 32000
constexpr float kSlope = 0.2f;
constexpr int   AS    = 68;         // act row stride (floats): 16B-aligned, benign banks
constexpr int   kWsDwPerD = 15360;  // per-d ws dwords: w0 3*1024, w1 3*2048, w2 3*2048

typedef __attribute__((ext_vector_type(8))) short bf16x8;
typedef __attribute__((ext_vector_type(4))) float f32x4;

// RNE-round two fp32 to bf16, return packed pair + the rounded values as fp32
__device__ __forceinline__ unsigned rne2(float x0, float x1, float &h0, float &h1) {
    unsigned u0 = __float_as_uint(x0), u1 = __float_as_uint(x1);
    unsigned r0 = u0 + 0x7FFFu + ((u0 >> 16) & 1u);
    unsigned r1 = u1 + 0x7FFFu + ((u1 >> 16) & 1u);
    h0 = __uint_as_float(r0 & 0xFFFF0000u);
    h1 = __uint_as_float(r1 & 0xFFFF0000u);
    return (r0 >> 16) | (r1 & 0xFFFF0000u);
}

// 3-way (24-bit) split: x ~= h1 + h2 + h3, all bf16. Used where SIGNS matter.
__device__ __forceinline__ void split3_2(float x0, float x1,
                                         unsigned &p1, unsigned &p2, unsigned &p3) {
    float h0, h1; p1 = rne2(x0, x1, h0, h1);
    float e0 = x0 - h0, e1 = x1 - h1;      // exact
    float m0, m1; p2 = rne2(e0, e1, m0, m1);
    float f0 = e0 - m0, f1 = e1 - m1;      // exact
    float t0, t1; p3 = rne2(f0, f1, t0, t1);
}

// 2-way (16-bit) split, for the Jacobian value chain
__device__ __forceinline__ void split2_2(float x0, float x1, unsigned &p1, unsigned &p2) {
    float h0, h1; p1 = rne2(x0, x1, h0, h1);
    float t0, t1; p2 = rne2(x0 - h0, x1 - h1, t0, t1);
}

union FragU { unsigned u[4]; bf16x8 v; };

__device__ __forceinline__ void splitA3(const float4 a0, const float4 a1,
                                        bf16x8 &A1, bf16x8 &A2, bf16x8 &A3) {
    FragU U1, U2, U3;
    split3_2(a0.x, a0.y, U1.u[0], U2.u[0], U3.u[0]);
    split3_2(a0.z, a0.w, U1.u[1], U2.u[1], U3.u[1]);
    split3_2(a1.x, a1.y, U1.u[2], U2.u[2], U3.u[2]);
    split3_2(a1.z, a1.w, U1.u[3], U2.u[3], U3.u[3]);
    A1 = U1.v; A2 = U2.v; A3 = U3.v;
}

__device__ __forceinline__ void splitA2(const float4 a0, const float4 a1,
                                        bf16x8 &A1, bf16x8 &A2) {
    FragU U1, U2;
    split2_2(a0.x, a0.y, U1.u[0], U2.u[0]);
    split2_2(a0.z, a0.w, U1.u[1], U2.u[1]);
    split2_2(a1.x, a1.y, U1.u[2], U2.u[2]);
    split2_2(a1.z, a1.w, U1.u[3], U2.u[3]);
    A1 = U1.v; A2 = U2.v;
}

// ---- prep: W0/W1/W2 -> 3-level bf16 B-fragments in d_ws ----
// B-frag (16x16x32): lane holds B[k=(lane>>4)*8+j][n=lane&15] = W[n][k], j=0..7.
// frag at dword offset ((nt*KT+kt)*64+lane)*4 within each level.
__global__ void prep_weights(const float* __restrict__ W0, const float* __restrict__ W1,
                             const float* __restrict__ W2, unsigned* __restrict__ ws) {
    int id = blockIdx.x * blockDim.x + threadIdx.x;   // 16*5120 total
    if (id >= 16 * 5120) return;
    int d = id / 5120, rem = id - d * 5120;
    unsigned* wd = ws + (size_t)d * kWsDwPerD;
    float x0, x1; unsigned o1, o2, o3;
    if (rem < 1024) {                                  // W0 (K=32, 1 ktile)
        int idx = rem, j2 = idx & 3, ln = (idx >> 2) & 63, nt = (idx >> 8) & 3;
        int n_ = nt * 16 + (ln & 15), k_ = ((ln >> 4) << 3) + 2 * j2;
        const float* g = W0 + (size_t)d * kH * 33;
        x0 = g[n_ * 33 + k_]; x1 = g[n_ * 33 + k_ + 1];
        o1 = idx; o2 = 1024 + idx; o3 = 2048 + idx;
    } else if (rem < 3072) {                           // W1 (K=64, 2 ktiles)
        int idx = rem - 1024, j2 = idx & 3, ln = (idx >> 2) & 63;
        int kt = (idx >> 8) & 1, nt = (idx >> 9) & 3;
        int n_ = nt * 16 + (ln & 15), k_ = kt * 32 + ((ln >> 4) << 3) + 2 * j2;
        const float* g = W1 + (size_t)d * kH * kH;
        x0 = g[n_ * 64 + k_]; x1 = g[n_ * 64 + k_ + 1];
        o1 = 3072 + idx; o2 = 5120 + idx; o3 = 7168 + idx;
    } else {                                           // W2
        int idx = rem - 3072, j2 = idx & 3, ln = (idx >> 2) & 63;
        int kt = (idx >> 8) & 1, nt = (idx >> 9) & 3;
        int n_ = nt * 16 + (ln & 15), k_ = kt * 32 + ((ln >> 4) << 3) + 2 * j2;
        const float* g = W2 + (size_t)d * kH * kH;
        x0 = g[n_ * 64 + k_]; x1 = g[n_ * 64 + k_ + 1];
        o1 = 9216 + idx; o2 = 11264 + idx; o3 = 13312 + idx;
    }
    unsigned p1, p2, p3; split3_2(x0, x1, p1, p2, p3);
    wd[o1] = p1; wd[o2] = p2; wd[o3] = p3;
}

// forward K=64 layer: 6-product bf16x3 (fp32-class accuracy; gates decided on this)
__device__ __forceinline__ void layer64_f(f32x4 acc[4], const float* actRow,
                                          const unsigned* w1, const unsigned* w2,
                                          const unsigned* w3, int lane) {
    const int q = lane >> 4;
    #pragma unroll
    for (int kt = 0; kt < 2; ++kt) {
        bf16x8 B1[4], B2[4], B3[4];
        #pragma unroll
        for (int nt = 0; nt < 4; ++nt) {
            const int off = ((nt * 2 + kt) * 64 + lane) << 2;
            B1[nt] = *(const bf16x8*)(w1 + off);
            B2[nt] = *(const bf16x8*)(w2 + off);
            B3[nt] = *(const bf16x8*)(w3 + off);
        }
        const float4 a0 = *(const float4*)(actRow + kt * 32 + q * 8);
        const float4 a1 = *(const float4*)(actRow + kt * 32 + q * 8 + 4);
        bf16x8 A1, A2, A3; splitA3(a0, a1, A1, A2, A3);
        #pragma unroll
        for (int nt = 0; nt < 4; ++nt) {
            acc[nt] = __builtin_amdgcn_mfma_f32_16x16x32_bf16(A3, B1[nt], acc[nt], 0, 0, 0);
            acc[nt] = __builtin_amdgcn_mfma_f32_16x16x32_bf16(A2, B2[nt], acc[nt], 0, 0, 0);
            acc[nt] = __builtin_amdgcn_mfma_f32_16x16x32_bf16(A1, B3[nt], acc[nt], 0, 0, 0);
            acc[nt] = __builtin_amdgcn_mfma_f32_16x16x32_bf16(A2, B1[nt], acc[nt], 0, 0, 0);
            acc[nt] = __builtin_amdgcn_mfma_f32_16x16x32_bf16(A1, B2[nt], acc[nt], 0, 0, 0);
            acc[nt] = __builtin_amdgcn_mfma_f32_16x16x32_bf16(A1, B1[nt], acc[nt], 0, 0, 0);
        }
    }
}

// Jacobian K=64 layer: 3-product 2-way split (values only, ~2^-16 rel, no signs)
__device__ __forceinline__ void layer64_j(f32x4 acc[4], const float* actRow,
                                          const unsigned* w1, const unsigned* w2,
                                          int lane) {
    const int q = lane >> 4;
    #pragma unroll
    for (int kt = 0; kt < 2; ++kt) {
        bf16x8 B1[4], B2[4];
        #pragma unroll
        for (int nt = 0; nt < 4; ++nt) {
            const int off = ((nt * 2 + kt) * 64 + lane) << 2;
            B1[nt] = *(const bf16x8*)(w1 + off);
            B2[nt] = *(const bf16x8*)(w2 + off);
        }
        const float4 a0 = *(const float4*)(actRow + kt * 32 + q * 8);
        const float4 a1 = *(const float4*)(actRow + kt * 32 + q * 8 + 4);
        bf16x8 A1, A2; splitA2(a0, a1, A1, A2);
        #pragma unroll
        for (int nt = 0; nt < 4; ++nt) {
            acc[nt] = __builtin_amdgcn_mfma_f32_16x16x32_bf16(A2, B1[nt], acc[nt], 0, 0, 0);
            acc[nt] = __builtin_amdgcn_mfma_f32_16x16x32_bf16(A1, B2[nt], acc[nt], 0, 0, 0);
            acc[nt] = __builtin_amdgcn_mfma_f32_16x16x32_bf16(A1, B1[nt], acc[nt], 0, 0, 0);
        }
    }
}

// Main: block = 512 threads = 8 waves; wave owns 16 tasks, all waves same d.
// C/D layout: unit = nt*16 + (lane&15), task-row = (lane>>4)*4 + reg.
// act[128][AS] fp32 LDS carries layer boundaries; waves touch disjoint rows.
__global__ __launch_bounds__(512, 2) void np_mfma_kernel(
    const float* __restrict__ x, const float* __restrict__ emb,
    const float* __restrict__ W0, const float* __restrict__ b0,
    const float* __restrict__ b1, const float* __restrict__ b2,
    const float* __restrict__ Wo, const float* __restrict__ bo,
    const unsigned* __restrict__ ws,
    float* __restrict__ out_res, float* __restrict__ out_ld)
{
    __shared__ __align__(16) float act[128 * AS];   // 34816 B

    const int tid  = threadIdx.x;
    const int lane = tid & 63;
    const int wave = __builtin_amdgcn_readfirstlane(tid >> 6);
    const int c = lane & 15, q = lane >> 4;
    const int tb0 = wave * 16;
    const int d  = blockIdx.y;
    const int n0 = blockIdx.x * 128 + tb0;

    const int nA = n0 + c;                           // A-side task (m = c)
    const int bb = nA / kLen;
    const size_t srcA = (size_t)bb * kT + (nA - bb * kLen) + 2;  // LAGS

    const float xm = x[srcA * kD + d];
    float xr[4];
    #pragma unroll
    for (int r = 0; r < 4; ++r) xr[r] = __shfl(xm, q * 4 + r, 16);

    const float* W0g = W0 + (size_t)d * kH * 33;
    float b0v[4], b1v[4], b2v[4], wov[4], w0xv[4];
    #pragma unroll
    for (int nt = 0; nt < 4; ++nt) {
        const int u = nt * 16 + c;
        b0v[nt]  = b0[d * kH + u];
        b1v[nt]  = b1[d * kH + u];
        b2v[nt]  = b2[d * kH + u];
        wov[nt]  = Wo[d * kH + u];
        w0xv[nt] = W0g[u * 33 + 32];
    }
    const float bov = bo[d];
    const unsigned* wd = ws + (size_t)d * kWsDwPerD;
    float* actRow = &act[(tb0 + c) * AS];

    unsigned m0 = 0, m1 = 0, m2 = 0;
    f32x4 acc[4];

    // ---------- L0 (K=32, 6-product): z0 = W0[:,:32]@emb + x*W0[:,32] + b0 ----------
    {
        bf16x8 B1[4], B2[4], B3[4];
        #pragma unroll
        for (int nt = 0; nt < 4; ++nt) {
            const int off = (nt * 64 + lane) << 2;
            B1[nt] = *(const bf16x8*)(wd + off);
            B2[nt] = *(const bf16x8*)(wd + 1024 + off);
            B3[nt] = *(const bf16x8*)(wd + 2048 + off);
        }
        const float4* ep = (const float4*)(emb + srcA * kE + q * 8);
        bf16x8 A1, A2, A3; splitA3(ep[0], ep[1], A1, A2, A3);
        #pragma unroll
        for (int nt = 0; nt < 4; ++nt) {
            f32x4 a;
            #pragma unroll
            for (int r = 0; r < 4; ++r) a[r] = fmaf(xr[r], w0xv[nt], b0v[nt]);
            a = __builtin_amdgcn_mfma_f32_16x16x32_bf16(A3, B1[nt], a, 0, 0, 0);
            a = __builtin_amdgcn_mfma_f32_16x16x32_bf16(A2, B2[nt], a, 0, 0, 0);
            a = __builtin_amdgcn_mfma_f32_16x16x32_bf16(A1, B3[nt], a, 0, 0, 0);
            a = __builtin_amdgcn_mfma_f32_16x16x32_bf16(A2, B1[nt], a, 0, 0, 0);
            a = __builtin_amdgcn_mfma_f32_16x16x32_bf16(A1, B2[nt], a, 0, 0, 0);
            a = __builtin_amdgcn_mfma_f32_16x16x32_bf16(A1, B1[nt], a, 0, 0, 0);
            acc[nt] = a;
        }
        #pragma unroll
        for (int nt = 0; nt < 4; ++nt)
            #pragma unroll
            for (int r = 0; r < 4; ++r) {
                float z = acc[nt][r];
                bool g = z >= 0.f;
                m0 |= (unsigned)g << (nt * 4 + r);
                act[(tb0 + q * 4 + r) * AS + nt * 16 + c] = g ? z : z * kSlope;
            }
    }

    // ---------- L1 ----------
    {
        #pragma unroll
        for (int nt = 0; nt < 4; ++nt) {
            f32x4 a;
            #pragma unroll
            for (int r = 0; r < 4; ++r) a[r] = b1v[nt];
            acc[nt] = a;
        }
        layer64_f(acc, actRow, wd + 3072, wd + 5120, wd + 7168, lane);
        #pragma unroll
        for (int nt = 0; nt < 4; ++nt)
            #pragma unroll
            for (int r = 0; r < 4; ++r) {
                float z = acc[nt][r];
                bool g = z >= 0.f;
                m1 |= (unsigned)g << (nt * 4 + r);
                act[(tb0 + q * 4 + r) * AS + nt * 16 + c] = g ? z : z * kSlope;
            }
    }

    // ---------- L2 + fused forward head ----------
    {
        #pragma unroll
        for (int nt = 0; nt < 4; ++nt) {
            f32x4 a;
            #pragma unroll
            for (int r = 0; r < 4; ++r) a[r] = b2v[nt];
            acc[nt] = a;
        }
        layer64_f(acc, actRow, wd + 9216, wd + 11264, wd + 13312, lane);
        float pr[4] = {0.f, 0.f, 0.f, 0.f};
        #pragma unroll
        for (int nt = 0; nt < 4; ++nt)
            #pragma unroll
            for (int r = 0; r < 4; ++r) {
                float z = acc[nt][r];
                bool g = z >= 0.f;
                m2 |= (unsigned)g << (nt * 4 + r);
                pr[r] = fmaf(wov[nt], g ? z : z * kSlope, pr[r]);
            }
        #pragma unroll
        for (int r = 0; r < 4; ++r) {
            #pragma unroll
            for (int s = 1; s < 16; s <<= 1) pr[r] += __shfl_xor(pr[r], s, 16);
        }
        if (c == 0) {
            #pragma unroll
            for (int r = 0; r < 4; ++r)
                out_res[(size_t)(n0 + q * 4 + r) * kD + d] = pr[r] + bov;
        }
    }

    // ---------- Jacobian t0 = g0 * W0[:, 32] ----------
    #pragma unroll
    for (int nt = 0; nt < 4; ++nt)
        #pragma unroll
        for (int r = 0; r < 4; ++r)
            act[(tb0 + q * 4 + r) * AS + nt * 16 + c] =
                (((m0 >> (nt * 4 + r)) & 1u) ? 1.f : kSlope) * w0xv[nt];

    // ---------- jac L1: t1 = g1 * (W1 @ t0) ----------
    {
        #pragma unroll
        for (int nt = 0; nt < 4; ++nt) acc[nt] = (f32x4){0.f, 0.f, 0.f, 0.f};
        layer64_j(acc, actRow, wd + 3072, wd + 5120, lane);
        #pragma unroll
        for (int nt = 0; nt < 4; ++nt)
            #pragma unroll
            for (int r = 0; r < 4; ++r)
                act[(tb0 + q * 4 + r) * AS + nt * 16 + c] =
                    (((m1 >> (nt * 4 + r)) & 1u) ? 1.f : kSlope) * acc[nt][r];
    }

    // ---------- jac L2 + fused Jacobian head ----------
    {
        #pragma unroll
        for (int nt = 0; nt < 4; ++nt) acc[nt] = (f32x4){0.f, 0.f, 0.f, 0.f};
        layer64_j(acc, actRow, wd + 9216, wd + 11264, lane);
        float pr[4] = {0.f, 0.f, 0.f, 0.f};
        #pragma unroll
        for (int nt = 0; nt < 4; ++nt)
            #pragma unroll
            for (int r = 0; r < 4; ++r) {
                float t = (((m2 >> (nt * 4 + r)) & 1u) ? 1.f : kSlope) * acc[nt][r];
                pr[r] = fmaf(wov[nt], t, pr[r]);
            }
        #pragma unroll
        for (int r = 0; r < 4; ++r) {
            #pragma unroll
            for (int s = 1; s < 16; s <<= 1) pr[r] += __shfl_xor(pr[r], s, 16);
        }
        if (c == 0) {
            #pragma unroll
            for (int r = 0; r < 4; ++r)
                atomicAdd(&out_ld[n0 + q * 4 + r], __logf(fabsf(pr[r])));
        }
    }
}

extern "C" void kernel_launch(void* const* d_in, const int* in_sizes, int n_in,
                              void* d_out, int out_size, void* d_ws, size_t ws_size,
                              hipStream_t stream) {
    const float* x  = (const float*)d_in[0];
    const float* em = (const float*)d_in[1];
    const float* W0 = (const float*)d_in[2];
    const float* b0 = (const float*)d_in[3];
    const float* W1 = (const float*)d_in[4];
    const float* b1 = (const float*)d_in[5];
    const float* W2 = (const float*)d_in[6];
    const float* b2 = (const float*)d_in[7];
    const float* Wo = (const float*)d_in[8];
    const float* bo = (const float*)d_in[9];

    float* out_res = (float*)d_out;                    // [N, D] residuals
    float* out_ld  = (float*)d_out + (size_t)kN * kD;  // [N] log|det J|
    unsigned* ws   = (unsigned*)d_ws;                  // 983,040 B of weight frags

    hipMemsetAsync(out_ld, 0, kN * sizeof(float), stream);
    prep_weights<<<dim3(16 * 5120 / 256), dim3(256), 0, stream>>>(W0, W1, W2, ws);
    np_mfma_kernel<<<dim3(kN / 128, kD), dim3(512), 0, stream>>>(
        x, em, W0, b0, b1, b2, Wo, bo, ws, out_res, out_ld);
}

// Round 8
// 221.047 us; speedup vs baseline: 12.0493x; 1.1241x over previous
//
#include <hip/hip_runtime.h>

// ---- problem constants ----
constexpr int   kT    = 1002;
constexpr int   kD    = 16;
constexpr int   kE    = 32;
constexpr int   kH    = 64;
constexpr int   kLen  = kT - 2;     // 1000
constexpr int   kN    = 32 * kLen;  // 32000
constexpr float kSlope = 0.2f;
constexpr int   AS    = 68;         // act row stride (floats)
constexpr int   kWsDwPerD = 15360;  // per-d ws dwords: w0 3*1024, w1 3*2048, w2 3*2048

typedef __attribute__((ext_vector_type(8))) short bf16x8;
typedef __attribute__((ext_vector_type(4))) float f32x4;

// RNE-round two fp32 to bf16 (packed via v_perm), return rounded values as fp32
__device__ __forceinline__ unsigned rne2(float x0, float x1, float &h0, float &h1) {
    unsigned u0 = __float_as_uint(x0), u1 = __float_as_uint(x1);
    unsigned r0 = u0 + 0x7FFFu + ((u0 >> 16) & 1u);
    unsigned r1 = u1 + 0x7FFFu + ((u1 >> 16) & 1u);
    h0 = __uint_as_float(r0 & 0xFFFF0000u);
    h1 = __uint_as_float(r1 & 0xFFFF0000u);
    return __builtin_amdgcn_perm(r1, r0, 0x07060302u);  // [r0.hi16 | r1.hi16<<16]
}

// 3-way (24-bit) split: x ~= h1+h2+h3, all bf16. Where SIGNS matter (forward).
__device__ __forceinline__ void split3_2(float x0, float x1,
                                         unsigned &p1, unsigned &p2, unsigned &p3) {
    float h0, h1; p1 = rne2(x0, x1, h0, h1);
    float e0 = x0 - h0, e1 = x1 - h1;      // exact
    float m0, m1; p2 = rne2(e0, e1, m0, m1);
    float f0 = e0 - m0, f1 = e1 - m1;      // exact
    float t0, t1; p3 = rne2(f0, f1, t0, t1);
}

// 2-way (16-bit) split, Jacobian value chain (no sign decisions)
__device__ __forceinline__ void split2_2(float x0, float x1, unsigned &p1, unsigned &p2) {
    float h0, h1; p1 = rne2(x0, x1, h0, h1);
    float t0, t1; p2 = rne2(x0 - h0, x1 - h1, t0, t1);
}

union FragU { unsigned u[4]; bf16x8 v; };

__device__ __forceinline__ void splitA3(const float4 a0, const float4 a1,
                                        bf16x8 &A1, bf16x8 &A2, bf16x8 &A3) {
    FragU U1, U2, U3;
    split3_2(a0.x, a0.y, U1.u[0], U2.u[0], U3.u[0]);
    split3_2(a0.z, a0.w, U1.u[1], U2.u[1], U3.u[1]);
    split3_2(a1.x, a1.y, U1.u[2], U2.u[2], U3.u[2]);
    split3_2(a1.z, a1.w, U1.u[3], U2.u[3], U3.u[3]);
    A1 = U1.v; A2 = U2.v; A3 = U3.v;
}

__device__ __forceinline__ void splitA2(const float4 a0, const float4 a1,
                                        bf16x8 &A1, bf16x8 &A2) {
    FragU U1, U2;
    split2_2(a0.x, a0.y, U1.u[0], U2.u[0]);
    split2_2(a0.z, a0.w, U1.u[1], U2.u[1]);
    split2_2(a1.x, a1.y, U1.u[2], U2.u[2]);
    split2_2(a1.z, a1.w, U1.u[3], U2.u[3]);
    A1 = U1.v; A2 = U2.v;
}

// ---- prep: W0/W1/W2 -> 3-level bf16 B-fragments in d_ws; also zeroes out_ld ----
// B-frag (16x16x32): lane holds B[k=(lane>>4)*8+j][n=lane&15] = W[n][k], j=0..7.
__global__ void prep_weights(const float* __restrict__ W0, const float* __restrict__ W1,
                             const float* __restrict__ W2, unsigned* __restrict__ ws,
                             float* __restrict__ out_ld) {
    int id = blockIdx.x * blockDim.x + threadIdx.x;   // 16*5120 total
    if (id < kN) out_ld[id] = 0.f;                    // replaces hipMemsetAsync
    if (id >= 16 * 5120) return;
    int d = id / 5120, rem = id - d * 5120;
    unsigned* wd = ws + (size_t)d * kWsDwPerD;
    float x0, x1; unsigned o1, o2, o3;
    if (rem < 1024) {                                  // W0 (K=32, 1 ktile)
        int idx = rem, j2 = idx & 3, ln = (idx >> 2) & 63, nt = (idx >> 8) & 3;
        int n_ = nt * 16 + (ln & 15), k_ = ((ln >> 4) << 3) + 2 * j2;
        const float* g = W0 + (size_t)d * kH * 33;
        x0 = g[n_ * 33 + k_]; x1 = g[n_ * 33 + k_ + 1];
        o1 = idx; o2 = 1024 + idx; o3 = 2048 + idx;
    } else if (rem < 3072) {                           // W1 (K=64, 2 ktiles)
        int idx = rem - 1024, j2 = idx & 3, ln = (idx >> 2) & 63;
        int kt = (idx >> 8) & 1, nt = (idx >> 9) & 3;
        int n_ = nt * 16 + (ln & 15), k_ = kt * 32 + ((ln >> 4) << 3) + 2 * j2;
        const float* g = W1 + (size_t)d * kH * kH;
        x0 = g[n_ * 64 + k_]; x1 = g[n_ * 64 + k_ + 1];
        o1 = 3072 + idx; o2 = 5120 + idx; o3 = 7168 + idx;
    } else {                                           // W2
        int idx = rem - 3072, j2 = idx & 3, ln = (idx >> 2) & 63;
        int kt = (idx >> 8) & 1, nt = (idx >> 9) & 3;
        int n_ = nt * 16 + (ln & 15), k_ = kt * 32 + ((ln >> 4) << 3) + 2 * j2;
        const float* g = W2 + (size_t)d * kH * kH;
        x0 = g[n_ * 64 + k_]; x1 = g[n_ * 64 + k_ + 1];
        o1 = 9216 + idx; o2 = 11264 + idx; o3 = 13312 + idx;
    }
    unsigned p1, p2, p3; split3_2(x0, x1, p1, p2, p3);
    wd[o1] = p1; wd[o2] = p2; wd[o3] = p3;
}

#define MFMA(A, B, C) __builtin_amdgcn_mfma_f32_16x16x32_bf16((A), (B), (C), 0, 0, 0)

// forward K=64 layer for 2 m-tiles: 6-product bf16x3, level-ordered so only one
// B level (16 VGPRs) is live at a time.
__device__ __forceinline__ void layer64_f(f32x4 acc[2][4],
                                          const float* r0, const float* r1,
                                          const unsigned* w1, const unsigned* w2,
                                          const unsigned* w3, int lane, int q) {
    #pragma unroll
    for (int kt = 0; kt < 2; ++kt) {
        bf16x8 A1[2], A2[2], A3[2];
        {
            const float4 a0 = *(const float4*)(r0 + kt * 32 + q * 8);
            const float4 a1 = *(const float4*)(r0 + kt * 32 + q * 8 + 4);
            splitA3(a0, a1, A1[0], A2[0], A3[0]);
            const float4 b0_ = *(const float4*)(r1 + kt * 32 + q * 8);
            const float4 b1_ = *(const float4*)(r1 + kt * 32 + q * 8 + 4);
            splitA3(b0_, b1_, A1[1], A2[1], A3[1]);
        }
        bf16x8 B[4];
        #pragma unroll
        for (int nt = 0; nt < 4; ++nt) B[nt] = *(const bf16x8*)(w1 + (((nt * 2 + kt) * 64 + lane) << 2));
        #pragma unroll
        for (int nt = 0; nt < 4; ++nt)
            #pragma unroll
            for (int mt = 0; mt < 2; ++mt) {
                acc[mt][nt] = MFMA(A3[mt], B[nt], acc[mt][nt]);
                acc[mt][nt] = MFMA(A2[mt], B[nt], acc[mt][nt]);
                acc[mt][nt] = MFMA(A1[mt], B[nt], acc[mt][nt]);
            }
        #pragma unroll
        for (int nt = 0; nt < 4; ++nt) B[nt] = *(const bf16x8*)(w2 + (((nt * 2 + kt) * 64 + lane) << 2));
        #pragma unroll
        for (int nt = 0; nt < 4; ++nt)
            #pragma unroll
            for (int mt = 0; mt < 2; ++mt) {
                acc[mt][nt] = MFMA(A2[mt], B[nt], acc[mt][nt]);
                acc[mt][nt] = MFMA(A1[mt], B[nt], acc[mt][nt]);
            }
        #pragma unroll
        for (int nt = 0; nt < 4; ++nt) B[nt] = *(const bf16x8*)(w3 + (((nt * 2 + kt) * 64 + lane) << 2));
        #pragma unroll
        for (int nt = 0; nt < 4; ++nt)
            #pragma unroll
            for (int mt = 0; mt < 2; ++mt)
                acc[mt][nt] = MFMA(A1[mt], B[nt], acc[mt][nt]);
    }
}

// Jacobian K=64 layer for 2 m-tiles: 3-product 2-way split
__device__ __forceinline__ void layer64_j(f32x4 acc[2][4],
                                          const float* r0, const float* r1,
                                          const unsigned* w1, const unsigned* w2,
                                          int lane, int q) {
    #pragma unroll
    for (int kt = 0; kt < 2; ++kt) {
        bf16x8 A1[2], A2[2];
        {
            const float4 a0 = *(const float4*)(r0 + kt * 32 + q * 8);
            const float4 a1 = *(const float4*)(r0 + kt * 32 + q * 8 + 4);
            splitA2(a0, a1, A1[0], A2[0]);
            const float4 b0_ = *(const float4*)(r1 + kt * 32 + q * 8);
            const float4 b1_ = *(const float4*)(r1 + kt * 32 + q * 8 + 4);
            splitA2(b0_, b1_, A1[1], A2[1]);
        }
        bf16x8 B[4];
        #pragma unroll
        for (int nt = 0; nt < 4; ++nt) B[nt] = *(const bf16x8*)(w1 + (((nt * 2 + kt) * 64 + lane) << 2));
        #pragma unroll
        for (int nt = 0; nt < 4; ++nt)
            #pragma unroll
            for (int mt = 0; mt < 2; ++mt) {
                acc[mt][nt] = MFMA(A2[mt], B[nt], acc[mt][nt]);
                acc[mt][nt] = MFMA(A1[mt], B[nt], acc[mt][nt]);
            }
        #pragma unroll
        for (int nt = 0; nt < 4; ++nt) B[nt] = *(const bf16x8*)(w2 + (((nt * 2 + kt) * 64 + lane) << 2));
        #pragma unroll
        for (int nt = 0; nt < 4; ++nt)
            #pragma unroll
            for (int mt = 0; mt < 2; ++mt)
                acc[mt][nt] = MFMA(A1[mt], B[nt], acc[mt][nt]);
    }
}

// Main: block = 256 threads = 4 waves; each wave owns 32 tasks (2 m-tiles of 16),
// all waves same d. C/D: task-row = mt*16 + (lane>>4)*4 + reg, unit = nt*16 + (lane&15).
// act[128][AS] fp32 LDS carries layer boundaries; waves touch disjoint rows -> no barriers.
__global__ __launch_bounds__(256, 2) void np_mfma_kernel(
    const float* __restrict__ x, const float* __restrict__ emb,
    const float* __restrict__ W0, const float* __restrict__ b0,
    const float* __restrict__ b1, const float* __restrict__ b2,
    const float* __restrict__ Wo, const float* __restrict__ bo,
    const unsigned* __restrict__ ws,
    float* __restrict__ out_res, float* __restrict__ out_ld)
{
    __shared__ __align__(16) float act[128 * AS];   // 34816 B

    const int tid  = threadIdx.x;
    const int lane = tid & 63;
    const int wave = __builtin_amdgcn_readfirstlane(tid >> 6);
    const int c = lane & 15, q = lane >> 4;
    const int tb = wave * 32;                        // block-local task base
    const int d  = blockIdx.y;
    const int nW = blockIdx.x * 128 + tb;            // global task base of wave

    // x for task nW + (q>>1)*16 + c  (64 lanes cover 32 tasks, 2-way redundant)
    {
        // nothing
    }
    const int nX  = nW + ((q >> 1) << 4) + c;
    const int bbX = nX / kLen;
    const float xm = x[((size_t)(bbX * kT + (nX - bbX * kLen) + 2)) * kD + d];
    float xr[2][4];
    #pragma unroll
    for (int mt = 0; mt < 2; ++mt)
        #pragma unroll
        for (int r = 0; r < 4; ++r)
            xr[mt][r] = __shfl(xm, mt * 32 + q * 4 + r, 64);  // src lane = 32*mt + row

    const float* W0g = W0 + (size_t)d * kH * 33;
    float b0v[4], wov[4], w0xv[4];
    #pragma unroll
    for (int nt = 0; nt < 4; ++nt) {
        const int u = nt * 16 + c;
        b0v[nt]  = b0[d * kH + u];
        wov[nt]  = Wo[d * kH + u];
        w0xv[nt] = W0g[u * 33 + 32];                 // last input column of W0
    }
    const float bov = bo[d];
    const unsigned* wd = ws + (size_t)d * kWsDwPerD;
    const float* r0 = &act[(tb + c) * AS];           // A rows for m-tile 0 / 1
    const float* r1 = &act[(tb + 16 + c) * AS];

    unsigned m0 = 0, m1 = 0, m2 = 0;                 // gate masks: bit = mt*16+nt*4+r
    f32x4 acc[2][4];

    // ---------- L0 (K=32): z0 = W0[:,:32]@emb + x*W0[:,32] + b0 ----------
    {
        bf16x8 A1[2], A2[2], A3[2];
        #pragma unroll
        for (int mt = 0; mt < 2; ++mt) {
            const int nA = nW + mt * 16 + c;
            const int bb = nA / kLen;
            const size_t src = (size_t)(bb * kT + (nA - bb * kLen) + 2);
            const float4* ep = (const float4*)(emb + src * kE + q * 8);
            splitA3(ep[0], ep[1], A1[mt], A2[mt], A3[mt]);
        }
        #pragma unroll
        for (int mt = 0; mt < 2; ++mt)
            #pragma unroll
            for (int nt = 0; nt < 4; ++nt) {
                f32x4 a;
                #pragma unroll
                for (int r = 0; r < 4; ++r) a[r] = fmaf(xr[mt][r], w0xv[nt], b0v[nt]);
                acc[mt][nt] = a;
            }
        bf16x8 B[4];
        #pragma unroll
        for (int nt = 0; nt < 4; ++nt) B[nt] = *(const bf16x8*)(wd + ((nt * 64 + lane) << 2));
        #pragma unroll
        for (int nt = 0; nt < 4; ++nt)
            #pragma unroll
            for (int mt = 0; mt < 2; ++mt) {
                acc[mt][nt] = MFMA(A3[mt], B[nt], acc[mt][nt]);
                acc[mt][nt] = MFMA(A2[mt], B[nt], acc[mt][nt]);
                acc[mt][nt] = MFMA(A1[mt], B[nt], acc[mt][nt]);
            }
        #pragma unroll
        for (int nt = 0; nt < 4; ++nt) B[nt] = *(const bf16x8*)(wd + 1024 + ((nt * 64 + lane) << 2));
        #pragma unroll
        for (int nt = 0; nt < 4; ++nt)
            #pragma unroll
            for (int mt = 0; mt < 2; ++mt) {
                acc[mt][nt] = MFMA(A2[mt], B[nt], acc[mt][nt]);
                acc[mt][nt] = MFMA(A1[mt], B[nt], acc[mt][nt]);
            }
        #pragma unroll
        for (int nt = 0; nt < 4; ++nt) B[nt] = *(const bf16x8*)(wd + 2048 + ((nt * 64 + lane) << 2));
        #pragma unroll
        for (int nt = 0; nt < 4; ++nt)
            #pragma unroll
            for (int mt = 0; mt < 2; ++mt)
                acc[mt][nt] = MFMA(A1[mt], B[nt], acc[mt][nt]);
        #pragma unroll
        for (int mt = 0; mt < 2; ++mt)
            #pragma unroll
            for (int nt = 0; nt < 4; ++nt)
                #pragma unroll
                for (int r = 0; r < 4; ++r) {
                    float z = acc[mt][nt][r];
                    bool g = z >= 0.f;
                    m0 |= (unsigned)g << (mt * 16 + nt * 4 + r);
                    act[(tb + mt * 16 + q * 4 + r) * AS + nt * 16 + c] = g ? z : z * kSlope;
                }
    }

    // ---------- L1 ----------
    {
        #pragma unroll
        for (int nt = 0; nt < 4; ++nt) {
            const float bv = b1[d * kH + nt * 16 + c];
            #pragma unroll
            for (int mt = 0; mt < 2; ++mt) {
                f32x4 a;
                #pragma unroll
                for (int r = 0; r < 4; ++r) a[r] = bv;
                acc[mt][nt] = a;
            }
        }
        layer64_f(acc, r0, r1, wd + 3072, wd + 5120, wd + 7168, lane, q);
        #pragma unroll
        for (int mt = 0; mt < 2; ++mt)
            #pragma unroll
            for (int nt = 0; nt < 4; ++nt)
                #pragma unroll
                for (int r = 0; r < 4; ++r) {
                    float z = acc[mt][nt][r];
                    bool g = z >= 0.f;
                    m1 |= (unsigned)g << (mt * 16 + nt * 4 + r);
                    act[(tb + mt * 16 + q * 4 + r) * AS + nt * 16 + c] = g ? z : z * kSlope;
                }
    }

    // ---------- L2 + fused forward head ----------
    {
        #pragma unroll
        for (int nt = 0; nt < 4; ++nt) {
            const float bv = b2[d * kH + nt * 16 + c];
            #pragma unroll
            for (int mt = 0; mt < 2; ++mt) {
                f32x4 a;
                #pragma unroll
                for (int r = 0; r < 4; ++r) a[r] = bv;
                acc[mt][nt] = a;
            }
        }
        layer64_f(acc, r0, r1, wd + 9216, wd + 11264, wd + 13312, lane, q);
        float pr[2][4] = {{0.f,0.f,0.f,0.f},{0.f,0.f,0.f,0.f}};
        #pragma unroll
        for (int mt = 0; mt < 2; ++mt)
            #pragma unroll
            for (int nt = 0; nt < 4; ++nt)
                #pragma unroll
                for (int r = 0; r < 4; ++r) {
                    float z = acc[mt][nt][r];
                    bool g = z >= 0.f;
                    m2 |= (unsigned)g << (mt * 16 + nt * 4 + r);
                    pr[mt][r] = fmaf(wov[nt], g ? z : z * kSlope, pr[mt][r]);
                }
        #pragma unroll
        for (int mt = 0; mt < 2; ++mt)
            #pragma unroll
            for (int r = 0; r < 4; ++r) {
                #pragma unroll
                for (int s = 1; s < 16; s <<= 1) pr[mt][r] += __shfl_xor(pr[mt][r], s, 16);
            }
        if (c == 0) {
            #pragma unroll
            for (int mt = 0; mt < 2; ++mt)
                #pragma unroll
                for (int r = 0; r < 4; ++r)
                    out_res[(size_t)(nW + mt * 16 + q * 4 + r) * kD + d] = pr[mt][r] + bov;
        }
    }

    // ---------- Jacobian t0 = g0 * W0[:, 32] ----------
    #pragma unroll
    for (int mt = 0; mt < 2; ++mt)
        #pragma unroll
        for (int nt = 0; nt < 4; ++nt)
            #pragma unroll
            for (int r = 0; r < 4; ++r)
                act[(tb + mt * 16 + q * 4 + r) * AS + nt * 16 + c] =
                    (((m0 >> (mt * 16 + nt * 4 + r)) & 1u) ? 1.f : kSlope) * w0xv[nt];

    // ---------- jac L1: t1 = g1 * (W1 @ t0) ----------
    {
        #pragma unroll
        for (int mt = 0; mt < 2; ++mt)
            #pragma unroll
            for (int nt = 0; nt < 4; ++nt) acc[mt][nt] = (f32x4){0.f, 0.f, 0.f, 0.f};
        layer64_j(acc, r0, r1, wd + 3072, wd + 5120, lane, q);
        #pragma unroll
        for (int mt = 0; mt < 2; ++mt)
            #pragma unroll
            for (int nt = 0; nt < 4; ++nt)
                #pragma unroll
                for (int r = 0; r < 4; ++r)
                    act[(tb + mt * 16 + q * 4 + r) * AS + nt * 16 + c] =
                        (((m1 >> (mt * 16 + nt * 4 + r)) & 1u) ? 1.f : kSlope) * acc[mt][nt][r];
    }

    // ---------- jac L2 + fused Jacobian head ----------
    {
        #pragma unroll
        for (int mt = 0; mt < 2; ++mt)
            #pragma unroll
            for (int nt = 0; nt < 4; ++nt) acc[mt][nt] = (f32x4){0.f, 0.f, 0.f, 0.f};
        layer64_j(acc, r0, r1, wd + 9216, wd + 11264, lane, q);
        float pr[2][4] = {{0.f,0.f,0.f,0.f},{0.f,0.f,0.f,0.f}};
        #pragma unroll
        for (int mt = 0; mt < 2; ++mt)
            #pragma unroll
            for (int nt = 0; nt < 4; ++nt)
                #pragma unroll
                for (int r = 0; r < 4; ++r) {
                    float t = (((m2 >> (mt * 16 + nt * 4 + r)) & 1u) ? 1.f : kSlope) * acc[mt][nt][r];
                    pr[mt][r] = fmaf(wov[nt], t, pr[mt][r]);
                }
        #pragma unroll
        for (int mt = 0; mt < 2; ++mt)
            #pragma unroll
            for (int r = 0; r < 4; ++r) {
                #pragma unroll
                for (int s = 1; s < 16; s <<= 1) pr[mt][r] += __shfl_xor(pr[mt][r], s, 16);
            }
        if (c == 0) {
            #pragma unroll
            for (int mt = 0; mt < 2; ++mt)
                #pragma unroll
                for (int r = 0; r < 4; ++r)
                    atomicAdd(&out_ld[nW + mt * 16 + q * 4 + r], __logf(fabsf(pr[mt][r])));
        }
    }
}

extern "C" void kernel_launch(void* const* d_in, const int* in_sizes, int n_in,
                              void* d_out, int out_size, void* d_ws, size_t ws_size,
                              hipStream_t stream) {
    const float* x  = (const float*)d_in[0];
    const float* em = (const float*)d_in[1];
    const float* W0 = (const float*)d_in[2];
    const float* b0 = (const float*)d_in[3];
    const float* W1 = (const float*)d_in[4];
    const float* b1 = (const float*)d_in[5];
    const float* W2 = (const float*)d_in[6];
    const float* b2 = (const float*)d_in[7];
    const float* Wo = (const float*)d_in[8];
    const float* bo = (const float*)d_in[9];

    float* out_res = (float*)d_out;                    // [N, D] residuals
    float* out_ld  = (float*)d_out + (size_t)kN * kD;  // [N] log|det J|
    unsigned* ws   = (unsigned*)d_ws;                  // 983,040 B of weight frags

    prep_weights<<<dim3(16 * 5120 / 256), dim3(256), 0, stream>>>(W0, W1, W2, ws, out_ld);
    np_mfma_kernel<<<dim3(kN / 128, kD), dim3(256), 0, stream>>>(
        x, em, W0, b0, b1, b2, Wo, bo, ws, out_res, out_ld);
}

// Round 9
// 219.128 us; speedup vs baseline: 12.1548x; 1.0088x over previous
//
#include <hip/hip_runtime.h>

// ---- problem constants ----
constexpr int   kT    = 1002;
constexpr int   kD    = 16;
constexpr int   kE    = 32;
constexpr int   kH    = 64;
constexpr int   kLen  = kT - 2;     // 1000
constexpr int   kN    = 32 * kLen;  // 32000
constexpr float kSlope = 0.2f;
constexpr int   AS    = 68;         // act row stride (floats)
constexpr int   kWsDwPerD = 15360;  // per-d ws dwords: w0 3*1024, w1 3*2048, w2 3*2048

typedef __attribute__((ext_vector_type(8))) short bf16x8;
typedef __attribute__((ext_vector_type(4))) float f32x4;

// RNE-round two fp32 to bf16 (packed), return rounded values as fp32.
// gfx950 has v_cvt_pk_bf16_f32 (RNE) — use it when the builtin exists;
// the manual sequence below is bit-identical (RNE, no NaNs in our data).
#if __has_builtin(__builtin_amdgcn_cvt_pk_bf16_f32)
typedef __attribute__((ext_vector_type(2))) __bf16 bf16x2;
__device__ __forceinline__ unsigned rne2(float x0, float x1, float &h0, float &h1) {
    bf16x2 p = __builtin_amdgcn_cvt_pk_bf16_f32(x0, x1);
    unsigned pk; __builtin_memcpy(&pk, &p, 4);
    h0 = __uint_as_float(pk << 16);
    h1 = __uint_as_float(pk & 0xFFFF0000u);
    return pk;
}
#else
__device__ __forceinline__ unsigned rne2(float x0, float x1, float &h0, float &h1) {
    unsigned u0 = __float_as_uint(x0), u1 = __float_as_uint(x1);
    unsigned r0 = u0 + 0x7FFFu + ((u0 >> 16) & 1u);
    unsigned r1 = u1 + 0x7FFFu + ((u1 >> 16) & 1u);
    h0 = __uint_as_float(r0 & 0xFFFF0000u);
    h1 = __uint_as_float(r1 & 0xFFFF0000u);
    return __builtin_amdgcn_perm(r1, r0, 0x07060302u);  // [r0.hi16 | r1.hi16<<16]
}
#endif

// 3-way (24-bit) split: x ~= h1+h2+h3, all bf16. Where SIGNS matter (forward).
__device__ __forceinline__ void split3_2(float x0, float x1,
                                         unsigned &p1, unsigned &p2, unsigned &p3) {
    float h0, h1; p1 = rne2(x0, x1, h0, h1);
    float e0 = x0 - h0, e1 = x1 - h1;      // exact
    float m0, m1; p2 = rne2(e0, e1, m0, m1);
    float f0 = e0 - m0, f1 = e1 - m1;      // exact
    float t0, t1; p3 = rne2(f0, f1, t0, t1);
}

// 2-way (16-bit) split, Jacobian value chain (no sign decisions)
__device__ __forceinline__ void split2_2(float x0, float x1, unsigned &p1, unsigned &p2) {
    float h0, h1; p1 = rne2(x0, x1, h0, h1);
    float t0, t1; p2 = rne2(x0 - h0, x1 - h1, t0, t1);
}

union FragU { unsigned u[4]; bf16x8 v; };

__device__ __forceinline__ void splitA3(const float4 a0, const float4 a1,
                                        bf16x8 &A1, bf16x8 &A2, bf16x8 &A3) {
    FragU U1, U2, U3;
    split3_2(a0.x, a0.y, U1.u[0], U2.u[0], U3.u[0]);
    split3_2(a0.z, a0.w, U1.u[1], U2.u[1], U3.u[1]);
    split3_2(a1.x, a1.y, U1.u[2], U2.u[2], U3.u[2]);
    split3_2(a1.z, a1.w, U1.u[3], U2.u[3], U3.u[3]);
    A1 = U1.v; A2 = U2.v; A3 = U3.v;
}

__device__ __forceinline__ void splitA2(const float4 a0, const float4 a1,
                                        bf16x8 &A1, bf16x8 &A2) {
    FragU U1, U2;
    split2_2(a0.x, a0.y, U1.u[0], U2.u[0]);
    split2_2(a0.z, a0.w, U1.u[1], U2.u[1]);
    split2_2(a1.x, a1.y, U1.u[2], U2.u[2]);
    split2_2(a1.z, a1.w, U1.u[3], U2.u[3]);
    A1 = U1.v; A2 = U2.v;
}

// ---- prep: W0/W1/W2 -> 3-level bf16 B-fragments in d_ws; also zeroes out_ld ----
// B-frag (16x16x32): lane holds B[k=(lane>>4)*8+j][n=lane&15] = W[n][k], j=0..7.
__global__ void prep_weights(const float* __restrict__ W0, const float* __restrict__ W1,
                             const float* __restrict__ W2, unsigned* __restrict__ ws,
                             float* __restrict__ out_ld) {
    int id = blockIdx.x * blockDim.x + threadIdx.x;   // 16*5120 total
    if (id < kN) out_ld[id] = 0.f;                    // replaces hipMemsetAsync
    if (id >= 16 * 5120) return;
    int d = id / 5120, rem = id - d * 5120;
    unsigned* wd = ws + (size_t)d * kWsDwPerD;
    float x0, x1; unsigned o1, o2, o3;
    if (rem < 1024) {                                  // W0 (K=32, 1 ktile)
        int idx = rem, j2 = idx & 3, ln = (idx >> 2) & 63, nt = (idx >> 8) & 3;
        int n_ = nt * 16 + (ln & 15), k_ = ((ln >> 4) << 3) + 2 * j2;
        const float* g = W0 + (size_t)d * kH * 33;
        x0 = g[n_ * 33 + k_]; x1 = g[n_ * 33 + k_ + 1];
        o1 = idx; o2 = 1024 + idx; o3 = 2048 + idx;
    } else if (rem < 3072) {                           // W1 (K=64, 2 ktiles)
        int idx = rem - 1024, j2 = idx & 3, ln = (idx >> 2) & 63;
        int kt = (idx >> 8) & 1, nt = (idx >> 9) & 3;
        int n_ = nt * 16 + (ln & 15), k_ = kt * 32 + ((ln >> 4) << 3) + 2 * j2;
        const float* g = W1 + (size_t)d * kH * kH;
        x0 = g[n_ * 64 + k_]; x1 = g[n_ * 64 + k_ + 1];
        o1 = 3072 + idx; o2 = 5120 + idx; o3 = 7168 + idx;
    } else {                                           // W2
        int idx = rem - 3072, j2 = idx & 3, ln = (idx >> 2) & 63;
        int kt = (idx >> 8) & 1, nt = (idx >> 9) & 3;
        int n_ = nt * 16 + (ln & 15), k_ = kt * 32 + ((ln >> 4) << 3) + 2 * j2;
        const float* g = W2 + (size_t)d * kH * kH;
        x0 = g[n_ * 64 + k_]; x1 = g[n_ * 64 + k_ + 1];
        o1 = 9216 + idx; o2 = 11264 + idx; o3 = 13312 + idx;
    }
    unsigned p1, p2, p3; split3_2(x0, x1, p1, p2, p3);
    wd[o1] = p1; wd[o2] = p2; wd[o3] = p3;
}

#define MFMA(A, B, C) __builtin_amdgcn_mfma_f32_16x16x32_bf16((A), (B), (C), 0, 0, 0)

// forward K=64 layer for 2 m-tiles: 6-product bf16x3, level-ordered so only one
// B level (16 VGPRs) is live at a time.
__device__ __forceinline__ void layer64_f(f32x4 acc[2][4],
                                          const float* r0, const float* r1,
                                          const unsigned* w1, const unsigned* w2,
                                          const unsigned* w3, int lane, int q) {
    #pragma unroll
    for (int kt = 0; kt < 2; ++kt) {
        bf16x8 A1[2], A2[2], A3[2];
        {
            const float4 a0 = *(const float4*)(r0 + kt * 32 + q * 8);
            const float4 a1 = *(const float4*)(r0 + kt * 32 + q * 8 + 4);
            splitA3(a0, a1, A1[0], A2[0], A3[0]);
            const float4 b0_ = *(const float4*)(r1 + kt * 32 + q * 8);
            const float4 b1_ = *(const float4*)(r1 + kt * 32 + q * 8 + 4);
            splitA3(b0_, b1_, A1[1], A2[1], A3[1]);
        }
        bf16x8 B[4];
        #pragma unroll
        for (int nt = 0; nt < 4; ++nt) B[nt] = *(const bf16x8*)(w1 + (((nt * 2 + kt) * 64 + lane) << 2));
        #pragma unroll
        for (int nt = 0; nt < 4; ++nt)
            #pragma unroll
            for (int mt = 0; mt < 2; ++mt) {
                acc[mt][nt] = MFMA(A3[mt], B[nt], acc[mt][nt]);
                acc[mt][nt] = MFMA(A2[mt], B[nt], acc[mt][nt]);
                acc[mt][nt] = MFMA(A1[mt], B[nt], acc[mt][nt]);
            }
        #pragma unroll
        for (int nt = 0; nt < 4; ++nt) B[nt] = *(const bf16x8*)(w2 + (((nt * 2 + kt) * 64 + lane) << 2));
        #pragma unroll
        for (int nt = 0; nt < 4; ++nt)
            #pragma unroll
            for (int mt = 0; mt < 2; ++mt) {
                acc[mt][nt] = MFMA(A2[mt], B[nt], acc[mt][nt]);
                acc[mt][nt] = MFMA(A1[mt], B[nt], acc[mt][nt]);
            }
        #pragma unroll
        for (int nt = 0; nt < 4; ++nt) B[nt] = *(const bf16x8*)(w3 + (((nt * 2 + kt) * 64 + lane) << 2));
        #pragma unroll
        for (int nt = 0; nt < 4; ++nt)
            #pragma unroll
            for (int mt = 0; mt < 2; ++mt)
                acc[mt][nt] = MFMA(A1[mt], B[nt], acc[mt][nt]);
    }
}

// Jacobian K=64 layer for 2 m-tiles: 3-product 2-way split
__device__ __forceinline__ void layer64_j(f32x4 acc[2][4],
                                          const float* r0, const float* r1,
                                          const unsigned* w1, const unsigned* w2,
                                          int lane, int q) {
    #pragma unroll
    for (int kt = 0; kt < 2; ++kt) {
        bf16x8 A1[2], A2[2];
        {
            const float4 a0 = *(const float4*)(r0 + kt * 32 + q * 8);
            const float4 a1 = *(const float4*)(r0 + kt * 32 + q * 8 + 4);
            splitA2(a0, a1, A1[0], A2[0]);
            const float4 b0_ = *(const float4*)(r1 + kt * 32 + q * 8);
            const float4 b1_ = *(const float4*)(r1 + kt * 32 + q * 8 + 4);
            splitA2(b0_, b1_, A1[1], A2[1]);
        }
        bf16x8 B[4];
        #pragma unroll
        for (int nt = 0; nt < 4; ++nt) B[nt] = *(const bf16x8*)(w1 + (((nt * 2 + kt) * 64 + lane) << 2));
        #pragma unroll
        for (int nt = 0; nt < 4; ++nt)
            #pragma unroll
            for (int mt = 0; mt < 2; ++mt) {
                acc[mt][nt] = MFMA(A2[mt], B[nt], acc[mt][nt]);
                acc[mt][nt] = MFMA(A1[mt], B[nt], acc[mt][nt]);
            }
        #pragma unroll
        for (int nt = 0; nt < 4; ++nt) B[nt] = *(const bf16x8*)(w2 + (((nt * 2 + kt) * 64 + lane) << 2));
        #pragma unroll
        for (int nt = 0; nt < 4; ++nt)
            #pragma unroll
            for (int mt = 0; mt < 2; ++mt)
                acc[mt][nt] = MFMA(A1[mt], B[nt], acc[mt][nt]);
    }
}

// Main: block = 128 threads = 2 waves; each wave owns 32 tasks (2 m-tiles of 16),
// all waves same d. LDS = 64 rows x AS = 17.4 KB -> ~9 blocks/CU resident (finer
// granularity than round-8's 256-thread/34.8 KB blocks).
// C/D: task-row = mt*16 + (lane>>4)*4 + reg, unit = nt*16 + (lane&15).
// act rows carry layer boundaries; waves touch disjoint rows -> no barriers.
__global__ __launch_bounds__(128, 2) void np_mfma_kernel(
    const float* __restrict__ x, const float* __restrict__ emb,
    const float* __restrict__ W0, const float* __restrict__ b0,
    const float* __restrict__ b1, const float* __restrict__ b2,
    const float* __restrict__ Wo, const float* __restrict__ bo,
    const unsigned* __restrict__ ws,
    float* __restrict__ out_res, float* __restrict__ out_ld)
{
    __shared__ __align__(16) float act[64 * AS];    // 17408 B

    const int tid  = threadIdx.x;
    const int lane = tid & 63;
    const int wave = __builtin_amdgcn_readfirstlane(tid >> 6);
    const int c = lane & 15, q = lane >> 4;
    const int tb = wave * 32;                        // block-local task base
    const int d  = blockIdx.y;
    const int nW = blockIdx.x * 64 + tb;             // global task base of wave

    // x for task nW + (q>>1)*16 + c  (64 lanes cover 32 tasks, 2-way redundant)
    const int nX  = nW + ((q >> 1) << 4) + c;
    const int bbX = nX / kLen;
    const float xm = x[((size_t)(bbX * kT + (nX - bbX * kLen) + 2)) * kD + d];
    float xr[2][4];
    #pragma unroll
    for (int mt = 0; mt < 2; ++mt)
        #pragma unroll
        for (int r = 0; r < 4; ++r)
            xr[mt][r] = __shfl(xm, mt * 32 + q * 4 + r, 64);  // src lane = 32*mt + row

    const float* W0g = W0 + (size_t)d * kH * 33;
    float b0v[4], wov[4], w0xv[4];
    #pragma unroll
    for (int nt = 0; nt < 4; ++nt) {
        const int u = nt * 16 + c;
        b0v[nt]  = b0[d * kH + u];
        wov[nt]  = Wo[d * kH + u];
        w0xv[nt] = W0g[u * 33 + 32];                 // last input column of W0
    }
    const float bov = bo[d];
    const unsigned* wd = ws + (size_t)d * kWsDwPerD;
    const float* r0 = &act[(tb + c) * AS];           // A rows for m-tile 0 / 1
    const float* r1 = &act[(tb + 16 + c) * AS];

    unsigned m0 = 0, m1 = 0, m2 = 0;                 // gate masks: bit = mt*16+nt*4+r
    f32x4 acc[2][4];

    // ---------- L0 (K=32): z0 = W0[:,:32]@emb + x*W0[:,32] + b0 ----------
    {
        bf16x8 A1[2], A2[2], A3[2];
        #pragma unroll
        for (int mt = 0; mt < 2; ++mt) {
            const int nA = nW + mt * 16 + c;
            const int bb = nA / kLen;
            const size_t src = (size_t)(bb * kT + (nA - bb * kLen) + 2);
            const float4* ep = (const float4*)(emb + src * kE + q * 8);
            splitA3(ep[0], ep[1], A1[mt], A2[mt], A3[mt]);
        }
        #pragma unroll
        for (int mt = 0; mt < 2; ++mt)
            #pragma unroll
            for (int nt = 0; nt < 4; ++nt) {
                f32x4 a;
                #pragma unroll
                for (int r = 0; r < 4; ++r) a[r] = fmaf(xr[mt][r], w0xv[nt], b0v[nt]);
                acc[mt][nt] = a;
            }
        bf16x8 B[4];
        #pragma unroll
        for (int nt = 0; nt < 4; ++nt) B[nt] = *(const bf16x8*)(wd + ((nt * 64 + lane) << 2));
        #pragma unroll
        for (int nt = 0; nt < 4; ++nt)
            #pragma unroll
            for (int mt = 0; mt < 2; ++mt) {
                acc[mt][nt] = MFMA(A3[mt], B[nt], acc[mt][nt]);
                acc[mt][nt] = MFMA(A2[mt], B[nt], acc[mt][nt]);
                acc[mt][nt] = MFMA(A1[mt], B[nt], acc[mt][nt]);
            }
        #pragma unroll
        for (int nt = 0; nt < 4; ++nt) B[nt] = *(const bf16x8*)(wd + 1024 + ((nt * 64 + lane) << 2));
        #pragma unroll
        for (int nt = 0; nt < 4; ++nt)
            #pragma unroll
            for (int mt = 0; mt < 2; ++mt) {
                acc[mt][nt] = MFMA(A2[mt], B[nt], acc[mt][nt]);
                acc[mt][nt] = MFMA(A1[mt], B[nt], acc[mt][nt]);
            }
        #pragma unroll
        for (int nt = 0; nt < 4; ++nt) B[nt] = *(const bf16x8*)(wd + 2048 + ((nt * 64 + lane) << 2));
        #pragma unroll
        for (int nt = 0; nt < 4; ++nt)
            #pragma unroll
            for (int mt = 0; mt < 2; ++mt)
                acc[mt][nt] = MFMA(A1[mt], B[nt], acc[mt][nt]);
        #pragma unroll
        for (int mt = 0; mt < 2; ++mt)
            #pragma unroll
            for (int nt = 0; nt < 4; ++nt)
                #pragma unroll
                for (int r = 0; r < 4; ++r) {
                    float z = acc[mt][nt][r];
                    bool g = z >= 0.f;
                    m0 |= (unsigned)g << (mt * 16 + nt * 4 + r);
                    act[(tb + mt * 16 + q * 4 + r) * AS + nt * 16 + c] = g ? z : z * kSlope;
                }
    }

    // ---------- L1 ----------
    {
        #pragma unroll
        for (int nt = 0; nt < 4; ++nt) {
            const float bv = b1[d * kH + nt * 16 + c];
            #pragma unroll
            for (int mt = 0; mt < 2; ++mt) {
                f32x4 a;
                #pragma unroll
                for (int r = 0; r < 4; ++r) a[r] = bv;
                acc[mt][nt] = a;
            }
        }
        layer64_f(acc, r0, r1, wd + 3072, wd + 5120, wd + 7168, lane, q);
        #pragma unroll
        for (int mt = 0; mt < 2; ++mt)
            #pragma unroll
            for (int nt = 0; nt < 4; ++nt)
                #pragma unroll
                for (int r = 0; r < 4; ++r) {
                    float z = acc[mt][nt][r];
                    bool g = z >= 0.f;
                    m1 |= (unsigned)g << (mt * 16 + nt * 4 + r);
                    act[(tb + mt * 16 + q * 4 + r) * AS + nt * 16 + c] = g ? z : z * kSlope;
                }
    }

    // ---------- L2 + fused forward head ----------
    {
        #pragma unroll
        for (int nt = 0; nt < 4; ++nt) {
            const float bv = b2[d * kH + nt * 16 + c];
            #pragma unroll
            for (int mt = 0; mt < 2; ++mt) {
                f32x4 a;
                #pragma unroll
                for (int r = 0; r < 4; ++r) a[r] = bv;
                acc[mt][nt] = a;
            }
        }
        layer64_f(acc, r0, r1, wd + 9216, wd + 11264, wd + 13312, lane, q);
        float pr[2][4] = {{0.f,0.f,0.f,0.f},{0.f,0.f,0.f,0.f}};
        #pragma unroll
        for (int mt = 0; mt < 2; ++mt)
            #pragma unroll
            for (int nt = 0; nt < 4; ++nt)
                #pragma unroll
                for (int r = 0; r < 4; ++r) {
                    float z = acc[mt][nt][r];
                    bool g = z >= 0.f;
                    m2 |= (unsigned)g << (mt * 16 + nt * 4 + r);
                    pr[mt][r] = fmaf(wov[nt], g ? z : z * kSlope, pr[mt][r]);
                }
        #pragma unroll
        for (int mt = 0; mt < 2; ++mt)
            #pragma unroll
            for (int r = 0; r < 4; ++r) {
                #pragma unroll
                for (int s = 1; s < 16; s <<= 1) pr[mt][r] += __shfl_xor(pr[mt][r], s, 16);
            }
        if (c == 0) {
            #pragma unroll
            for (int mt = 0; mt < 2; ++mt)
                #pragma unroll
                for (int r = 0; r < 4; ++r)
                    out_res[(size_t)(nW + mt * 16 + q * 4 + r) * kD + d] = pr[mt][r] + bov;
        }
    }

    // ---------- Jacobian t0 = g0 * W0[:, 32] ----------
    #pragma unroll
    for (int mt = 0; mt < 2; ++mt)
        #pragma unroll
        for (int nt = 0; nt < 4; ++nt)
            #pragma unroll
            for (int r = 0; r < 4; ++r)
                act[(tb + mt * 16 + q * 4 + r) * AS + nt * 16 + c] =
                    (((m0 >> (mt * 16 + nt * 4 + r)) & 1u) ? 1.f : kSlope) * w0xv[nt];

    // ---------- jac L1: t1 = g1 * (W1 @ t0) ----------
    {
        #pragma unroll
        for (int mt = 0; mt < 2; ++mt)
            #pragma unroll
            for (int nt = 0; nt < 4; ++nt) acc[mt][nt] = (f32x4){0.f, 0.f, 0.f, 0.f};
        layer64_j(acc, r0, r1, wd + 3072, wd + 5120, lane, q);
        #pragma unroll
        for (int mt = 0; mt < 2; ++mt)
            #pragma unroll
            for (int nt = 0; nt < 4; ++nt)
                #pragma unroll
                for (int r = 0; r < 4; ++r)
                    act[(tb + mt * 16 + q * 4 + r) * AS + nt * 16 + c] =
                        (((m1 >> (mt * 16 + nt * 4 + r)) & 1u) ? 1.f : kSlope) * acc[mt][nt][r];
    }

    // ---------- jac L2 + fused Jacobian head ----------
    {
        #pragma unroll
        for (int mt = 0; mt < 2; ++mt)
            #pragma unroll
            for (int nt = 0; nt < 4; ++nt) acc[mt][nt] = (f32x4){0.f, 0.f, 0.f, 0.f};
        layer64_j(acc, r0, r1, wd + 9216, wd + 11264, lane, q);
        float pr[2][4] = {{0.f,0.f,0.f,0.f},{0.f,0.f,0.f,0.f}};
        #pragma unroll
        for (int mt = 0; mt < 2; ++mt)
            #pragma unroll
            for (int nt = 0; nt < 4; ++nt)
                #pragma unroll
                for (int r = 0; r < 4; ++r) {
                    float t = (((m2 >> (mt * 16 + nt * 4 + r)) & 1u) ? 1.f : kSlope) * acc[mt][nt][r];
                    pr[mt][r] = fmaf(wov[nt], t, pr[mt][r]);
                }
        #pragma unroll
        for (int mt = 0; mt < 2; ++mt)
            #pragma unroll
            for (int r = 0; r < 4; ++r) {
                #pragma unroll
                for (int s = 1; s < 16; s <<= 1) pr[mt][r] += __shfl_xor(pr[mt][r], s, 16);
            }
        if (c == 0) {
            #pragma unroll
            for (int mt = 0; mt < 2; ++mt)
                #pragma unroll
                for (int r = 0; r < 4; ++r)
                    atomicAdd(&out_ld[nW + mt * 16 + q * 4 + r], __logf(fabsf(pr[mt][r])));
        }
    }
}

extern "C" void kernel_launch(void* const* d_in, const int* in_sizes, int n_in,
                              void* d_out, int out_size, void* d_ws, size_t ws_size,
                              hipStream_t stream) {
    const float* x  = (const float*)d_in[0];
    const float* em = (const float*)d_in[1];
    const float* W0 = (const float*)d_in[2];
    const float* b0 = (const float*)d_in[3];
    const float* W1 = (const float*)d_in[4];
    const float* b1 = (const float*)d_in[5];
    const float* W2 = (const float*)d_in[6];
    const float* b2 = (const float*)d_in[7];
    const float* Wo = (const float*)d_in[8];
    const float* bo = (const float*)d_in[9];

    float* out_res = (float*)d_out;                    // [N, D] residuals
    float* out_ld  = (float*)d_out + (size_t)kN * kD;  // [N] log|det J|
    unsigned* ws   = (unsigned*)d_ws;                  // 983,040 B of weight frags

    prep_weights<<<dim3(16 * 5120 / 256), dim3(256), 0, stream>>>(W0, W1, W2, ws, out_ld);
    np_mfma_kernel<<<dim3(kN / 64, kD), dim3(128), 0, stream>>>(
        x, em, W0, b0, b1, b2, Wo, bo, ws, out_res, out_ld);
}

// Round 11
// 184.819 us; speedup vs baseline: 14.4112x; 1.1856x over previous
//
#include <hip/hip_runtime.h>

// ---- problem constants ----
constexpr int   kT    = 1002;
constexpr int   kD    = 16;
constexpr int   kE    = 32;
constexpr int   kH    = 64;
constexpr int   kLen  = kT - 2;     // 1000
constexpr int   kN    = 32 * kLen;  // 32000
constexpr float kSlope = 0.2f;
constexpr int   AS    = 68;         // act row stride (floats)
// per-d ws dwords: fwd bf16 3-level (w0 3*1024 @0, w1 3*2048 @3072, w2 3*2048 @9216),
// jac fp16 2-level (w1 @15360/17408, w2 @19456/21504)
constexpr int   kWsDwPerD = 23552;

typedef __attribute__((ext_vector_type(8))) short bf16x8;
typedef __attribute__((ext_vector_type(4))) float f32x4;
typedef __attribute__((ext_vector_type(2))) __fp16 fp16x2;     // cvt_pkrtz result type
typedef __attribute__((ext_vector_type(8))) _Float16 f16x8;    // MFMA f16 operand type

// ---------------- bf16 splits (forward path: signs matter, 24-bit) ----------------
__device__ __forceinline__ unsigned rne2(float x0, float x1, float &h0, float &h1) {
    unsigned u0 = __float_as_uint(x0), u1 = __float_as_uint(x1);
    unsigned r0 = u0 + 0x7FFFu + ((u0 >> 16) & 1u);
    unsigned r1 = u1 + 0x7FFFu + ((u1 >> 16) & 1u);
    h0 = __uint_as_float(r0 & 0xFFFF0000u);
    h1 = __uint_as_float(r1 & 0xFFFF0000u);
    return __builtin_amdgcn_perm(r1, r0, 0x07060302u);  // [r0.hi16 | r1.hi16<<16]
}

__device__ __forceinline__ void split3_2(float x0, float x1,
                                         unsigned &p1, unsigned &p2, unsigned &p3) {
    float h0, h1; p1 = rne2(x0, x1, h0, h1);
    float e0 = x0 - h0, e1 = x1 - h1;      // exact
    float m0, m1; p2 = rne2(e0, e1, m0, m1);
    float f0 = e0 - m0, f1 = e1 - m1;      // exact
    float t0, t1; p3 = rne2(f0, f1, t0, t1);
}

union FragU { unsigned u[4]; bf16x8 v; };

__device__ __forceinline__ void splitA3(const float4 a0, const float4 a1,
                                        bf16x8 &A1, bf16x8 &A2, bf16x8 &A3) {
    FragU U1, U2, U3;
    split3_2(a0.x, a0.y, U1.u[0], U2.u[0], U3.u[0]);
    split3_2(a0.z, a0.w, U1.u[1], U2.u[1], U3.u[1]);
    split3_2(a1.x, a1.y, U1.u[2], U2.u[2], U3.u[2]);
    split3_2(a1.z, a1.w, U1.u[3], U2.u[3], U3.u[3]);
    A1 = U1.v; A2 = U2.v; A3 = U3.v;
}

// ---------------- fp16 splits (Jacobian path: values only, ~21-bit) ----------------
// v_cvt_pkrtz_f16_f32 is a single HW op. Worst-case fp16 denormal flush on the
// residual level costs only ~2^-11 relative on dJ -> ~5e-4 on log|dJ| (harmless).
// NOTE: the builtin returns a __fp16 vector (NOT _Float16) — move bits via memcpy.
__device__ __forceinline__ void split2h(float x0, float x1, unsigned &p1, unsigned &p2) {
    fp16x2 h = __builtin_amdgcn_cvt_pkrtz(x0, x1);
    __builtin_memcpy(&p1, &h, 4);
    fp16x2 l = __builtin_amdgcn_cvt_pkrtz(x0 - (float)h[0], x1 - (float)h[1]);
    __builtin_memcpy(&p2, &l, 4);
}

union FragH { unsigned u[4]; f16x8 v; };

__device__ __forceinline__ void splitA2h(const float4 a0, const float4 a1,
                                         f16x8 &A1, f16x8 &A2) {
    FragH U1, U2;
    split2h(a0.x, a0.y, U1.u[0], U2.u[0]);
    split2h(a0.z, a0.w, U1.u[1], U2.u[1]);
    split2h(a1.x, a1.y, U1.u[2], U2.u[2]);
    split2h(a1.z, a1.w, U1.u[3], U2.u[3]);
    A1 = U1.v; A2 = U2.v;
}

// ---- prep: weights -> B-fragments in d_ws; also zeroes out_ld ----
// B-frag (16x16x32): lane holds B[k=(lane>>4)*8+j][n=lane&15] = W[n][k], j=0..7.
__global__ void prep_weights(const float* __restrict__ W0, const float* __restrict__ W1,
                             const float* __restrict__ W2, unsigned* __restrict__ ws,
                             float* __restrict__ out_ld) {
    int id = blockIdx.x * blockDim.x + threadIdx.x;   // 16*9216 total
    if (id < kN) out_ld[id] = 0.f;                    // replaces hipMemsetAsync
    if (id >= 16 * 9216) return;
    int d = id / 9216, rem = id - d * 9216;
    unsigned* wd = ws + (size_t)d * kWsDwPerD;

    if (rem < 5120) {                                  // forward bf16 3-level
        float x0, x1; unsigned o1, o2, o3;
        if (rem < 1024) {                              // W0 (K=32, 1 ktile)
            int idx = rem, j2 = idx & 3, ln = (idx >> 2) & 63, nt = (idx >> 8) & 3;
            int n_ = nt * 16 + (ln & 15), k_ = ((ln >> 4) << 3) + 2 * j2;
            const float* g = W0 + (size_t)d * kH * 33;
            x0 = g[n_ * 33 + k_]; x1 = g[n_ * 33 + k_ + 1];
            o1 = idx; o2 = 1024 + idx; o3 = 2048 + idx;
        } else if (rem < 3072) {                       // W1 (K=64, 2 ktiles)
            int idx = rem - 1024, j2 = idx & 3, ln = (idx >> 2) & 63;
            int kt = (idx >> 8) & 1, nt = (idx >> 9) & 3;
            int n_ = nt * 16 + (ln & 15), k_ = kt * 32 + ((ln >> 4) << 3) + 2 * j2;
            const float* g = W1 + (size_t)d * kH * kH;
            x0 = g[n_ * 64 + k_]; x1 = g[n_ * 64 + k_ + 1];
            o1 = 3072 + idx; o2 = 5120 + idx; o3 = 7168 + idx;
        } else {                                       // W2
            int idx = rem - 3072, j2 = idx & 3, ln = (idx >> 2) & 63;
            int kt = (idx >> 8) & 1, nt = (idx >> 9) & 3;
            int n_ = nt * 16 + (ln & 15), k_ = kt * 32 + ((ln >> 4) << 3) + 2 * j2;
            const float* g = W2 + (size_t)d * kH * kH;
            x0 = g[n_ * 64 + k_]; x1 = g[n_ * 64 + k_ + 1];
            o1 = 9216 + idx; o2 = 11264 + idx; o3 = 13312 + idx;
        }
        unsigned p1, p2, p3; split3_2(x0, x1, p1, p2, p3);
        wd[o1] = p1; wd[o2] = p2; wd[o3] = p3;
    } else {                                           // jacobian fp16 2-level
        int idx, base; const float* g;
        if (rem < 7168) { idx = rem - 5120; base = 15360; g = W1 + (size_t)d * kH * kH; }
        else            { idx = rem - 7168; base = 19456; g = W2 + (size_t)d * kH * kH; }
        int j2 = idx & 3, ln = (idx >> 2) & 63;
        int kt = (idx >> 8) & 1, nt = (idx >> 9) & 3;
        int n_ = nt * 16 + (ln & 15), k_ = kt * 32 + ((ln >> 4) << 3) + 2 * j2;
        float x0 = g[n_ * 64 + k_], x1 = g[n_ * 64 + k_ + 1];
        unsigned p1, p2; split2h(x0, x1, p1, p2);
        wd[base + idx] = p1; wd[base + 2048 + idx] = p2;
    }
}

#define MFMA(A, B, C)  __builtin_amdgcn_mfma_f32_16x16x32_bf16((A), (B), (C), 0, 0, 0)
#define MFMAH(A, B, C) __builtin_amdgcn_mfma_f32_16x16x32_f16((A), (B), (C), 0, 0, 0)

// forward K=64 layer, 2 m-tiles: 6-product bf16x3, level-ordered (one B level live)
__device__ __forceinline__ void layer64_f(f32x4 acc[2][4],
                                          const float* r0, const float* r1,
                                          const unsigned* w1, const unsigned* w2,
                                          const unsigned* w3, int lane, int q) {
    #pragma unroll
    for (int kt = 0; kt < 2; ++kt) {
        bf16x8 A1[2], A2[2], A3[2];
        {
            const float4 a0 = *(const float4*)(r0 + kt * 32 + q * 8);
            const float4 a1 = *(const float4*)(r0 + kt * 32 + q * 8 + 4);
            splitA3(a0, a1, A1[0], A2[0], A3[0]);
            const float4 b0_ = *(const float4*)(r1 + kt * 32 + q * 8);
            const float4 b1_ = *(const float4*)(r1 + kt * 32 + q * 8 + 4);
            splitA3(b0_, b1_, A1[1], A2[1], A3[1]);
        }
        bf16x8 B[4];
        #pragma unroll
        for (int nt = 0; nt < 4; ++nt) B[nt] = *(const bf16x8*)(w1 + (((nt * 2 + kt) * 64 + lane) << 2));
        #pragma unroll
        for (int nt = 0; nt < 4; ++nt)
            #pragma unroll
            for (int mt = 0; mt < 2; ++mt) {
                acc[mt][nt] = MFMA(A3[mt], B[nt], acc[mt][nt]);
                acc[mt][nt] = MFMA(A2[mt], B[nt], acc[mt][nt]);
                acc[mt][nt] = MFMA(A1[mt], B[nt], acc[mt][nt]);
            }
        #pragma unroll
        for (int nt = 0; nt < 4; ++nt) B[nt] = *(const bf16x8*)(w2 + (((nt * 2 + kt) * 64 + lane) << 2));
        #pragma unroll
        for (int nt = 0; nt < 4; ++nt)
            #pragma unroll
            for (int mt = 0; mt < 2; ++mt) {
                acc[mt][nt] = MFMA(A2[mt], B[nt], acc[mt][nt]);
                acc[mt][nt] = MFMA(A1[mt], B[nt], acc[mt][nt]);
            }
        #pragma unroll
        for (int nt = 0; nt < 4; ++nt) B[nt] = *(const bf16x8*)(w3 + (((nt * 2 + kt) * 64 + lane) << 2));
        #pragma unroll
        for (int nt = 0; nt < 4; ++nt)
            #pragma unroll
            for (int mt = 0; mt < 2; ++mt)
                acc[mt][nt] = MFMA(A1[mt], B[nt], acc[mt][nt]);
    }
}

// Jacobian K=64 layer, 2 m-tiles: fp16 2-way split, 3 products (values only)
__device__ __forceinline__ void layer64_jh(f32x4 acc[2][4],
                                           const float* r0, const float* r1,
                                           const unsigned* wl1, const unsigned* wl2,
                                           int lane, int q) {
    #pragma unroll
    for (int kt = 0; kt < 2; ++kt) {
        f16x8 A1[2], A2[2];
        {
            const float4 a0 = *(const float4*)(r0 + kt * 32 + q * 8);
            const float4 a1 = *(const float4*)(r0 + kt * 32 + q * 8 + 4);
            splitA2h(a0, a1, A1[0], A2[0]);
            const float4 b0_ = *(const float4*)(r1 + kt * 32 + q * 8);
            const float4 b1_ = *(const float4*)(r1 + kt * 32 + q * 8 + 4);
            splitA2h(b0_, b1_, A1[1], A2[1]);
        }
        f16x8 B[4];
        #pragma unroll
        for (int nt = 0; nt < 4; ++nt) B[nt] = *(const f16x8*)(wl1 + (((nt * 2 + kt) * 64 + lane) << 2));
        #pragma unroll
        for (int nt = 0; nt < 4; ++nt)
            #pragma unroll
            for (int mt = 0; mt < 2; ++mt) {
                acc[mt][nt] = MFMAH(A2[mt], B[nt], acc[mt][nt]);
                acc[mt][nt] = MFMAH(A1[mt], B[nt], acc[mt][nt]);
            }
        #pragma unroll
        for (int nt = 0; nt < 4; ++nt) B[nt] = *(const f16x8*)(wl2 + (((nt * 2 + kt) * 64 + lane) << 2));
        #pragma unroll
        for (int nt = 0; nt < 4; ++nt)
            #pragma unroll
            for (int mt = 0; mt < 2; ++mt)
                acc[mt][nt] = MFMAH(A1[mt], B[nt], acc[mt][nt]);
    }
}

// Main: block = 128 threads = 2 waves; each wave owns 32 tasks (2 m-tiles of 16),
// all waves same d. C/D: task-row = mt*16 + (lane>>4)*4 + reg, unit = nt*16 + (lane&15).
// act rows carry layer boundaries; waves touch disjoint rows -> no barriers.
__global__ __launch_bounds__(128, 2) void np_mfma_kernel(
    const float* __restrict__ x, const float* __restrict__ emb,
    const float* __restrict__ W0, const float* __restrict__ b0,
    const float* __restrict__ b1, const float* __restrict__ b2,
    const float* __restrict__ Wo, const float* __restrict__ bo,
    const unsigned* __restrict__ ws,
    float* __restrict__ out_res, float* __restrict__ out_ld)
{
    __shared__ __align__(16) float act[64 * AS];    // 17408 B

    const int tid  = threadIdx.x;
    const int lane = tid & 63;
    const int wave = __builtin_amdgcn_readfirstlane(tid >> 6);
    const int c = lane & 15, q = lane >> 4;
    const int tb = wave * 32;                        // block-local task base
    const int d  = blockIdx.y;
    const int nW = blockIdx.x * 64 + tb;             // global task base of wave

    // x for task nW + (q>>1)*16 + c  (64 lanes cover 32 tasks, 2-way redundant)
    const int nX  = nW + ((q >> 1) << 4) + c;
    const int bbX = nX / kLen;
    const float xm = x[((size_t)(bbX * kT + (nX - bbX * kLen) + 2)) * kD + d];
    float xr[2][4];
    #pragma unroll
    for (int mt = 0; mt < 2; ++mt)
        #pragma unroll
        for (int r = 0; r < 4; ++r)
            xr[mt][r] = __shfl(xm, mt * 32 + q * 4 + r, 64);  // src lane = 32*mt + row

    const float* W0g = W0 + (size_t)d * kH * 33;
    float b0v[4], wov[4], w0xv[4];
    #pragma unroll
    for (int nt = 0; nt < 4; ++nt) {
        const int u = nt * 16 + c;
        b0v[nt]  = b0[d * kH + u];
        wov[nt]  = Wo[d * kH + u];
        w0xv[nt] = W0g[u * 33 + 32];                 // last input column of W0
    }
    const float bov = bo[d];
    const unsigned* wd = ws + (size_t)d * kWsDwPerD;
    const float* r0 = &act[(tb + c) * AS];           // A rows for m-tile 0 / 1
    const float* r1 = &act[(tb + 16 + c) * AS];

    unsigned m0 = 0, m1 = 0, m2 = 0;                 // gate masks: bit = mt*16+nt*4+r
    f32x4 acc[2][4];

    // ---------- L0 (K=32): z0 = W0[:,:32]@emb + x*W0[:,32] + b0 ----------
    {
        bf16x8 A1[2], A2[2], A3[2];
        #pragma unroll
        for (int mt = 0; mt < 2; ++mt) {
            const int nA = nW + mt * 16 + c;
            const int bb = nA / kLen;
            const size_t src = (size_t)(bb * kT + (nA - bb * kLen) + 2);
            const float4* ep = (const float4*)(emb + src * kE + q * 8);
            splitA3(ep[0], ep[1], A1[mt], A2[mt], A3[mt]);
        }
        #pragma unroll
        for (int mt = 0; mt < 2; ++mt)
            #pragma unroll
            for (int nt = 0; nt < 4; ++nt) {
                f32x4 a;
                #pragma unroll
                for (int r = 0; r < 4; ++r) a[r] = fmaf(xr[mt][r], w0xv[nt], b0v[nt]);
                acc[mt][nt] = a;
            }
        bf16x8 B[4];
        #pragma unroll
        for (int nt = 0; nt < 4; ++nt) B[nt] = *(const bf16x8*)(wd + ((nt * 64 + lane) << 2));
        #pragma unroll
        for (int nt = 0; nt < 4; ++nt)
            #pragma unroll
            for (int mt = 0; mt < 2; ++mt) {
                acc[mt][nt] = MFMA(A3[mt], B[nt], acc[mt][nt]);
                acc[mt][nt] = MFMA(A2[mt], B[nt], acc[mt][nt]);
                acc[mt][nt] = MFMA(A1[mt], B[nt], acc[mt][nt]);
            }
        #pragma unroll
        for (int nt = 0; nt < 4; ++nt) B[nt] = *(const bf16x8*)(wd + 1024 + ((nt * 64 + lane) << 2));
        #pragma unroll
        for (int nt = 0; nt < 4; ++nt)
            #pragma unroll
            for (int mt = 0; mt < 2; ++mt) {
                acc[mt][nt] = MFMA(A2[mt], B[nt], acc[mt][nt]);
                acc[mt][nt] = MFMA(A1[mt], B[nt], acc[mt][nt]);
            }
        #pragma unroll
        for (int nt = 0; nt < 4; ++nt) B[nt] = *(const bf16x8*)(wd + 2048 + ((nt * 64 + lane) << 2));
        #pragma unroll
        for (int nt = 0; nt < 4; ++nt)
            #pragma unroll
            for (int mt = 0; mt < 2; ++mt)
                acc[mt][nt] = MFMA(A1[mt], B[nt], acc[mt][nt]);
        #pragma unroll
        for (int mt = 0; mt < 2; ++mt)
            #pragma unroll
            for (int nt = 0; nt < 4; ++nt)
                #pragma unroll
                for (int r = 0; r < 4; ++r) {
                    float z = acc[mt][nt][r];
                    m0 |= (unsigned)(z >= 0.f) << (mt * 16 + nt * 4 + r);
                    act[(tb + mt * 16 + q * 4 + r) * AS + nt * 16 + c] = fmaxf(z, z * kSlope);
                }
    }

    // ---------- L1 ----------
    {
        #pragma unroll
        for (int nt = 0; nt < 4; ++nt) {
            const float bv = b1[d * kH + nt * 16 + c];
            #pragma unroll
            for (int mt = 0; mt < 2; ++mt) {
                f32x4 a;
                #pragma unroll
                for (int r = 0; r < 4; ++r) a[r] = bv;
                acc[mt][nt] = a;
            }
        }
        layer64_f(acc, r0, r1, wd + 3072, wd + 5120, wd + 7168, lane, q);
        #pragma unroll
        for (int mt = 0; mt < 2; ++mt)
            #pragma unroll
            for (int nt = 0; nt < 4; ++nt)
                #pragma unroll
                for (int r = 0; r < 4; ++r) {
                    float z = acc[mt][nt][r];
                    m1 |= (unsigned)(z >= 0.f) << (mt * 16 + nt * 4 + r);
                    act[(tb + mt * 16 + q * 4 + r) * AS + nt * 16 + c] = fmaxf(z, z * kSlope);
                }
    }

    // ---------- L2 + fused forward head ----------
    {
        #pragma unroll
        for (int nt = 0; nt < 4; ++nt) {
            const float bv = b2[d * kH + nt * 16 + c];
            #pragma unroll
            for (int mt = 0; mt < 2; ++mt) {
                f32x4 a;
                #pragma unroll
                for (int r = 0; r < 4; ++r) a[r] = bv;
                acc[mt][nt] = a;
            }
        }
        layer64_f(acc, r0, r1, wd + 9216, wd + 11264, wd + 13312, lane, q);
        float pr[2][4] = {{0.f,0.f,0.f,0.f},{0.f,0.f,0.f,0.f}};
        #pragma unroll
        for (int mt = 0; mt < 2; ++mt)
            #pragma unroll
            for (int nt = 0; nt < 4; ++nt)
                #pragma unroll
                for (int r = 0; r < 4; ++r) {
                    float z = acc[mt][nt][r];
                    m2 |= (unsigned)(z >= 0.f) << (mt * 16 + nt * 4 + r);
                    pr[mt][r] = fmaf(wov[nt], fmaxf(z, z * kSlope), pr[mt][r]);
                }
        #pragma unroll
        for (int mt = 0; mt < 2; ++mt)
            #pragma unroll
            for (int r = 0; r < 4; ++r) {
                #pragma unroll
                for (int s = 1; s < 16; s <<= 1) pr[mt][r] += __shfl_xor(pr[mt][r], s, 16);
            }
        if (c == 0) {
            #pragma unroll
            for (int mt = 0; mt < 2; ++mt)
                #pragma unroll
                for (int r = 0; r < 4; ++r)
                    out_res[(size_t)(nW + mt * 16 + q * 4 + r) * kD + d] = pr[mt][r] + bov;
        }
    }

    // ---------- Jacobian t0 = g0 * W0[:, 32] ----------
    #pragma unroll
    for (int mt = 0; mt < 2; ++mt)
        #pragma unroll
        for (int nt = 0; nt < 4; ++nt)
            #pragma unroll
            for (int r = 0; r < 4; ++r)
                act[(tb + mt * 16 + q * 4 + r) * AS + nt * 16 + c] =
                    (((m0 >> (mt * 16 + nt * 4 + r)) & 1u) ? 1.f : kSlope) * w0xv[nt];

    // ---------- jac L1: t1 = g1 * (W1 @ t0)  [fp16 2-way, 3 products] ----------
    {
        #pragma unroll
        for (int mt = 0; mt < 2; ++mt)
            #pragma unroll
            for (int nt = 0; nt < 4; ++nt) acc[mt][nt] = (f32x4){0.f, 0.f, 0.f, 0.f};
        layer64_jh(acc, r0, r1, wd + 15360, wd + 17408, lane, q);
        #pragma unroll
        for (int mt = 0; mt < 2; ++mt)
            #pragma unroll
            for (int nt = 0; nt < 4; ++nt)
                #pragma unroll
                for (int r = 0; r < 4; ++r)
                    act[(tb + mt * 16 + q * 4 + r) * AS + nt * 16 + c] =
                        (((m1 >> (mt * 16 + nt * 4 + r)) & 1u) ? 1.f : kSlope) * acc[mt][nt][r];
    }

    // ---------- jac L2 + fused Jacobian head ----------
    {
        #pragma unroll
        for (int mt = 0; mt < 2; ++mt)
            #pragma unroll
            for (int nt = 0; nt < 4; ++nt) acc[mt][nt] = (f32x4){0.f, 0.f, 0.f, 0.f};
        layer64_jh(acc, r0, r1, wd + 19456, wd + 21504, lane, q);
        float pr[2][4] = {{0.f,0.f,0.f,0.f},{0.f,0.f,0.f,0.f}};
        #pragma unroll
        for (int mt = 0; mt < 2; ++mt)
            #pragma unroll
            for (int nt = 0; nt < 4; ++nt)
                #pragma unroll
                for (int r = 0; r < 4; ++r) {
                    float t = (((m2 >> (mt * 16 + nt * 4 + r)) & 1u) ? 1.f : kSlope) * acc[mt][nt][r];
                    pr[mt][r] = fmaf(wov[nt], t, pr[mt][r]);
                }
        #pragma unroll
        for (int mt = 0; mt < 2; ++mt)
            #pragma unroll
            for (int r = 0; r < 4; ++r) {
                #pragma unroll
                for (int s = 1; s < 16; s <<= 1) pr[mt][r] += __shfl_xor(pr[mt][r], s, 16);
            }
        if (c == 0) {
            #pragma unroll
            for (int mt = 0; mt < 2; ++mt)
                #pragma unroll
                for (int r = 0; r < 4; ++r)
                    atomicAdd(&out_ld[nW + mt * 16 + q * 4 + r], __logf(fabsf(pr[mt][r])));
        }
    }
}

extern "C" void kernel_launch(void* const* d_in, const int* in_sizes, int n_in,
                              void* d_out, int out_size, void* d_ws, size_t ws_size,
                              hipStream_t stream) {
    const float* x  = (const float*)d_in[0];
    const float* em = (const float*)d_in[1];
    const float* W0 = (const float*)d_in[2];
    const float* b0 = (const float*)d_in[3];
    const float* W1 = (const float*)d_in[4];
    const float* b1 = (const float*)d_in[5];
    const float* W2 = (const float*)d_in[6];
    const float* b2 = (const float*)d_in[7];
    const float* Wo = (const float*)d_in[8];
    const float* bo = (const float*)d_in[9];

    float* out_res = (float*)d_out;                    // [N, D] residuals
    float* out_ld  = (float*)d_out + (size_t)kN * kD;  // [N] log|det J|
    unsigned* ws   = (unsigned*)d_ws;                  // 1,507,328 B of weight frags

    prep_weights<<<dim3(16 * 9216 / 256), dim3(256), 0, stream>>>(W0, W1, W2, ws, out_ld);
    np_mfma_kernel<<<dim3(kN / 64, kD), dim3(128), 0, stream>>>(
        x, em, W0, b0, b1, b2, Wo, bo, ws, out_res, out_ld);
}